// Round 15
// baseline (385.308 us; speedup 1.0000x reference)
//
#include <hip/hip_runtime.h>
#include <hip/hip_fp8.h>

#define B_ 2
#define H_ 224
#define W_ 224
#define HW_ 50176
#define E_ 768
#define M_ 196

typedef __attribute__((ext_vector_type(8))) short short8;
typedef __attribute__((ext_vector_type(4))) float floatx4;

__device__ __forceinline__ float bf2f(ushort u){ return __uint_as_float(((unsigned)u)<<16); }
__device__ __forceinline__ ushort f2bf(float f){
  unsigned b = __float_as_uint(f);
  b += 0x7fffu + ((b>>16)&1u);
  return (ushort)(b>>16);
}
__device__ __forceinline__ unsigned char f2f8(float f){
  __hip_fp8_e4m3 t(f);
  return (unsigned char)t.__x;
}
__device__ __forceinline__ float f82f(unsigned char b){
  __hip_fp8_e4m3 t; t.__x = (__hip_fp8_storage_t)b;
  return (float)t;
}

// async global->LDS 16B (direct-to-shared DMA; LDS dst = wave-uniform base + lane*16)
__device__ __forceinline__ void ld_g2l16(const void* g, void* l){
  __builtin_amdgcn_global_load_lds((const __attribute__((address_space(1))) unsigned int*)g,
                                   (__attribute__((address_space(3))) unsigned int*)l, 16, 0, 0);
}

// ---------------- merged prep: blocks 0..1727 fold BN2 into conv2 weights,
// layout wt2[tap][kc][co][8]; blocks 1728..1735 fold BN1 -> A[64 co][32 k]
__global__ void prep_k(const float* __restrict__ w2, const float* __restrict__ cb2,
                       const float* __restrict__ g2, const float* __restrict__ be2,
                       const float* __restrict__ mn2, const float* __restrict__ vr2,
                       ushort* __restrict__ wt2, float* __restrict__ bias2,
                       const float* __restrict__ w1, const float* __restrict__ cb1,
                       const float* __restrict__ g1, const float* __restrict__ be1,
                       const float* __restrict__ mn1, const float* __restrict__ vr1,
                       ushort* __restrict__ wA, float* __restrict__ bias1){
  if (blockIdx.x < 1728){
    int t = blockIdx.x*256 + threadIdx.x;      // 768*576 exactly
    int co = t / 576, kp = t % 576;
    int tap = kp >> 6, ci = kp & 63;
    float inv = g2[co] * rsqrtf(vr2[co] + 1e-5f);
    wt2[((tap*8 + (ci>>3))*768 + co)*8 + (ci&7)] = f2bf(w2[co*576 + ci*9 + tap] * inv);
    if (kp == 0) bias2[co] = cb2[co]*inv + be2[co] - mn2[co]*inv;
  } else {
    int t = (blockIdx.x-1728)*256 + threadIdx.x;  // 2048 exactly
    int co = t >> 5, k = t & 31;
    float inv = g1[co] * rsqrtf(vr1[co] + 1e-5f);
    float val = 0.f;
    if (k < 27){
      int tap = k / 3, ci = k % 3;
      val = w1[co*27 + ci*9 + tap] * inv;
    }
    wA[co*32 + k] = f2bf(val);
    if (k == 0) bias1[co] = cb1[co]*inv + be1[co] - mn1[co]*inv;
  }
}

// ---------------- conv1 + BN1 + ReLU via bf16 MFMA implicit GEMM (K=27 pad 32)
__launch_bounds__(256)
__global__ void conv1_k(const float* __restrict__ img, const ushort* __restrict__ wA,
                        const float* __restrict__ bias1, ushort* __restrict__ xbf){
  __shared__ float HL[3*18*20];          // fp32 halo, row pad 20
  __shared__ ushort IC[256*40];          // im2col [px][32k pad40]
  __shared__ ushort AW[64*40];           // weights [co][32k pad40]
  __shared__ float b1s[64];
  int tid = threadIdx.x;
  int b = blockIdx.x / 196, tile = blockIdx.x % 196;
  int tr = tile / 14, tc = tile % 14;
  int h0 = tr*16, w0 = tc*16;
  for (int idx = tid; idx < 972; idx += 256){
    int ci = idx / 324, rem = idx % 324;
    int r = rem / 18, c = rem % 18;
    int hh = h0 + r - 1, ww = w0 + c - 1;
    float v = (hh>=0 && hh<H_ && ww>=0 && ww<W_) ? img[((b*3+ci)*H_+hh)*W_+ww] : 0.f;
    HL[ci*360 + r*20 + c] = v;
  }
  {
    int row = tid >> 2, cp = (tid&3)*8;
    uint4 v = *reinterpret_cast<const uint4*>(&wA[row*32 + cp]);
    *reinterpret_cast<uint4*>(&AW[row*40 + cp]) = v;
  }
  if (tid < 64) b1s[tid] = bias1[tid];
  __syncthreads();
  {
    int pr = tid >> 4, pc = tid & 15;
    ushort tmp[32];
    #pragma unroll
    for (int ky=0; ky<3; ky++)
      #pragma unroll
      for (int kx=0; kx<3; kx++)
        #pragma unroll
        for (int ci=0; ci<3; ci++)
          tmp[(ky*3+kx)*3+ci] = f2bf(HL[ci*360 + (pr+ky)*20 + (pc+kx)]);
    #pragma unroll
    for (int k=27; k<32; k++) tmp[k] = 0;
    #pragma unroll
    for (int j=0; j<4; j++)
      *reinterpret_cast<uint4*>(&IC[tid*40 + j*8]) = *reinterpret_cast<const uint4*>(&tmp[j*8]);
  }
  __syncthreads();
  int lane = tid & 63, wave = tid >> 6;
  int q = lane >> 4, l15 = lane & 15;
  short8 af[4], bfr[4];
  #pragma unroll
  for (int f=0; f<4; f++)
    af[f] = *reinterpret_cast<const short8*>(&AW[(f*16+l15)*40 + q*8]);
  #pragma unroll
  for (int f=0; f<4; f++)
    bfr[f] = *reinterpret_cast<const short8*>(&IC[(wave*64+f*16+l15)*40 + q*8]);
  floatx4 acc[4][4];
  #pragma unroll
  for (int fc=0; fc<4; fc++)
    #pragma unroll
    for (int fp=0; fp<4; fp++){
      floatx4 z = (floatx4){0.f,0.f,0.f,0.f};
      acc[fc][fp] = __builtin_amdgcn_mfma_f32_16x16x32_bf16(af[fc], bfr[fp], z, 0,0,0);
    }
  #pragma unroll
  for (int fp=0; fp<4; fp++){
    int pxl = wave*64 + fp*16 + l15;
    size_t gp = (size_t)b*HW_ + (size_t)(h0 + (pxl>>4))*W_ + (w0 + (pxl&15));
    #pragma unroll
    for (int fc=0; fc<4; fc++){
      int co4 = fc*16 + q*4;
      ushort o[4];
      #pragma unroll
      for (int r=0; r<4; r++) o[r] = f2bf(fmaxf(acc[fc][fp][r] + b1s[co4+r], 0.f));
      *reinterpret_cast<uint2*>(&xbf[gp*64 + co4]) = *reinterpret_cast<const uint2*>(o);
    }
  }
}

// ---------------- edge conv + gradient_map + similarity + per-seg counts/sim sums + seg copy
__global__ void edge_k(const float* __restrict__ img, const int* __restrict__ seg,
                       const float* __restrict__ ew, float* __restrict__ out,
                       float* __restrict__ counts, float* __restrict__ sims,
                       int* __restrict__ scnt){
  __shared__ float cnt[196], ssum[196];
  int tid = threadIdx.x;
  if (tid < 196){ cnt[tid]=0.f; ssum[tid]=0.f; }
  __syncthreads();
  int p = blockIdx.x*256 + tid;
  int b = p / HW_; int r = p % HW_; int h = r / W_; int w = r % W_;
  float e0=0.f, e1=0.f;
  #pragma unroll
  for (int ky=0;ky<3;ky++){
    int hh=h+ky-1;
    #pragma unroll
    for (int kx=0;kx<3;kx++){
      int ww=w+kx-1;
      float gv=0.f;
      if (hh>=0&&hh<H_&&ww>=0&&ww<W_){
        int base = b*3*HW_ + hh*W_ + ww;
        gv=(img[base]+img[base+HW_]+img[base+2*HW_])*(1.f/3.f);
      }
      e0 += gv*ew[ky*3+kx];
      e1 += gv*ew[9+ky*3+kx];
    }
  }
  float gm = sqrtf(e0*e0+e1*e1+1e-8f);
  out[301056 + p] = gm;
  int sg = seg[p];
  out[401408 + p] = (float)sg;
  float sim = fminf(fmaxf(1.f-gm,0.f),1.f);
  atomicAdd(&cnt[sg], 1.f);
  atomicAdd(&ssum[sg], sim);
  __syncthreads();
  if (tid < 196){
    int gid = b*196 + tid;
    float c = cnt[tid];
    atomicAdd(&counts[gid], c);
    atomicAdd(&sims[gid], ssum[tid]);
    atomicAdd(&scnt[b*196+tid], (int)c);
  }
}

// ---------------- per-batch exclusive scan of segment counts
__global__ void scan_k(const int* __restrict__ scnt, int* __restrict__ offs, int* __restrict__ curs){
  __shared__ int a[256];
  int s = blockIdx.x, tid = threadIdx.x;
  a[tid] = (tid<196)? scnt[s*196+tid] : 0;
  __syncthreads();
  for (int d=1; d<256; d<<=1){
    int v = a[tid];
    int u = (tid>=d)? a[tid-d] : 0;
    __syncthreads();
    a[tid] = v+u;
    __syncthreads();
  }
  if (tid<=196) offs[s*200+tid] = tid ? a[tid-1] : 0;
  if (tid<196)  curs[s*196+tid] = tid ? a[tid-1] : 0;
}

// ---------------- scatter global pixel indices into per-(batch,segment) lists
__global__ void scatter_k(const int* __restrict__ seg, int* __restrict__ curs, int* __restrict__ list){
  int p = blockIdx.x*256+threadIdx.x;
  int b = p / HW_;
  int pos = atomicAdd(&curs[b*196+seg[p]], 1);
  list[b*HW_ + pos] = p;            // global pixel index
}

// ---------------- conv2 (dilated 3x3, 64->768) + BN2 + ReLU via bf16 MFMA implicit GEMM
// v8 = v6 K-half structure (4-plane X halo, W half-tap double buffer via
// global_load_lds, LDS 31.7 KB -> 5 blocks/CU) + fp8-e4m3 feats epilogue.
// fp8 halves the per-block in-flight write set (16 KB): 5 blocks/CU x 32 CU
// = 2.5 MB < 4 MB L2/XCD — under the measured write-combining limit that
// thrashed at bf16 (R11: WRITE 734 MB). Occupancy hides the 18 barrier drains.
__launch_bounds__(256, 5)
__global__ void conv2_k(const ushort* __restrict__ xbf, const ushort* __restrict__ wt2,
                        const float* __restrict__ bias2, unsigned char* __restrict__ feats){
  __shared__ ushort XH[4*1920];   // 4 k-chunk planes x 240 px x 8 ushorts = 15360 B
  __shared__ ushort WL[2*4096];   // 2 buf x 4 planes x 128 co x 8 ushorts = 16384 B
  int tid = threadIdx.x;
  int lane = tid & 63, wave = tid >> 6;
  int wc = wave >> 1, wp = wave & 1;
  int q = lane >> 4, l15 = lane & 15;
  int bt = blockIdx.x / 392, tile = blockIdx.x % 392;
  int tr = tile / 14, tc = tile % 14;
  int co0 = blockIdx.y * 128;
  int h0 = tr*8, w0 = tc*16;

  // halo source for this thread's pixel (px = tid, 240 px of 12x20 halo)
  int px = tid;
  const uint4* hsrc = nullptr;
  bool ok = false;
  if (px < 240){
    int hr = px / 20, wcol = px % 20;
    int hh = h0 + hr - 2, ww = w0 + wcol - 2;
    ok = (hh>=0 && hh<H_ && ww>=0 && ww<W_);
    int hc = ok ? hh : 0, wcl = ok ? ww : 0;
    hsrc = reinterpret_cast<const uint4*>(&xbf[(((size_t)bt*H_+hc)*W_+wcl)*64]);
  }

  floatx4 acc[4][4];
  for (int i=0;i<4;i++) for (int j=0;j<4;j++) acc[i][j] = (floatx4){0.f,0.f,0.f,0.f};

  // per-lane invariant bases (ushort indices)
  int abase = q*1024 + (wc*64 + l15)*8;            // W: + bsel*4096 + f*128
  int xbase = q*1920 + (wp*80 + l15)*8;            // X: + (dyr*20+dxr)*8 + f*160

  #pragma unroll
  for (int kh = 0; kh < 2; kh++){
    // stage X halo planes kh*4 .. kh*4+3 (previous half's reads completed at
    // the trailing barrier of the last tap)
    if (px < 240){
      #pragma unroll
      for (int c=0; c<4; c++){
        uint4 v = ok ? hsrc[kh*4 + c] : make_uint4(0u,0u,0u,0u);
        *reinterpret_cast<uint4*>(&XH[c*1920 + px*8]) = v;
      }
    }
    if (kh == 0){
      // prefetch W(tap 0, half 0) into buf 0
      #pragma unroll
      for (int j=0;j<2;j++){
        int idx = tid + 256*j;                       // kc_local*128 + co_local
        int srci = (((idx>>7))*768 + co0 + (idx&127))*8;
        ld_g2l16(&wt2[srci], &WL[(idx & ~63)*8]);
      }
    }
    __syncthreads();
    #pragma unroll
    for (int t=0; t<9; t++){
      const int hs = kh*9 + t;
      const int bsel = hs & 1;
      if (hs < 17){                                  // prefetch next (tap, half)
        const int nt = (t+1 < 9) ? t+1 : 0;
        const int nh = (t+1 < 9) ? kh : 1;
        const int nb = (hs+1) & 1;
        #pragma unroll
        for (int j=0;j<2;j++){
          int idx = tid + 256*j;
          int srci = ((nt*8 + nh*4 + (idx>>7))*768 + co0 + (idx&127))*8;
          ld_g2l16(&wt2[srci], &WL[nb*4096 + (idx & ~63)*8]);
        }
      }
      const int dyr = (t/3)*2, dxr = (t%3)*2;
      const int xoff = (dyr*20 + dxr)*8;             // compile-time (unrolled)
      short8 af[4], bx[4];
      #pragma unroll
      for (int f=0; f<4; f++)
        af[f] = *reinterpret_cast<const short8*>(&WL[bsel*4096 + abase + f*128]);
      #pragma unroll
      for (int f=0; f<4; f++)
        bx[f] = *reinterpret_cast<const short8*>(&XH[xbase + xoff + f*160]);
      #pragma unroll
      for (int fc=0; fc<4; fc++)
        #pragma unroll
        for (int fp=0; fp<4; fp++)
          acc[fc][fp] = __builtin_amdgcn_mfma_f32_16x16x32_bf16(af[fc], bx[fp], acc[fc][fp], 0,0,0);
      __syncthreads();
    }
  }

  // epilogue: bias + relu, fp8 pack, direct 4B stores (co = wc*64+fc*16+q*4+r)
  #pragma unroll
  for (int fc=0; fc<4; fc++){
    float4 bs = *reinterpret_cast<const float4*>(&bias2[co0 + wc*64 + fc*16 + q*4]);
    #pragma unroll
    for (int fp=0; fp<4; fp++){
      int pxl = wp*64 + fp*16 + l15;
      size_t pgl = (size_t)bt*HW_ + (size_t)(tr*8 + (pxl>>4))*W_ + tc*16 + (pxl&15);
      unsigned ob = (unsigned)f2f8(fmaxf(acc[fc][fp][0] + bs.x, 0.f))
                  | ((unsigned)f2f8(fmaxf(acc[fc][fp][1] + bs.y, 0.f)) << 8)
                  | ((unsigned)f2f8(fmaxf(acc[fc][fp][2] + bs.z, 0.f)) << 16)
                  | ((unsigned)f2f8(fmaxf(acc[fc][fp][3] + bs.w, 0.f)) << 24);
      *reinterpret_cast<unsigned*>(&feats[pgl*768 + co0 + wc*64 + fc*16 + q*4]) = ob;
    }
  }
}

// ---------------- gather pooling: full-image lists, 8-way split, fp8 feats (4B/lane)
__global__ void pool_k(const unsigned char* __restrict__ feats, const int* __restrict__ list,
                       const int* __restrict__ offs, float* __restrict__ meansum,
                       float* __restrict__ maxv){
  int m = blockIdx.x, qu = blockIdx.y, b = blockIdx.z, tid = threadIdx.x;
  int base = offs[b*200+m], end = offs[b*200+m+1];
  int len = end - base;
  int b0 = base + ((len*qu) >> 3);
  int b1 = base + ((len*(qu+1)) >> 3);
  const int* lp = &list[b*HW_];
  int co4 = tid*4;
  float s0=0.f,s1=0.f,s2=0.f,s3=0.f;
  float m0=0.f,m1=0.f,m2=0.f,m3=0.f;
  int i = b0;
  #define ACC(v) { \
    float f0=f82f((unsigned char)((v)&0xff)),      f1=f82f((unsigned char)(((v)>>8)&0xff)); \
    float f2=f82f((unsigned char)(((v)>>16)&0xff)), f3=f82f((unsigned char)((v)>>24)); \
    s0+=f0; s1+=f1; s2+=f2; s3+=f3; \
    m0=fmaxf(m0,f0); m1=fmaxf(m1,f1); m2=fmaxf(m2,f2); m3=fmaxf(m3,f3); }
  for (; i+3 < b1; i += 4){
    unsigned va = *reinterpret_cast<const unsigned*>(&feats[(size_t)lp[i  ]*768 + co4]);
    unsigned vb = *reinterpret_cast<const unsigned*>(&feats[(size_t)lp[i+1]*768 + co4]);
    unsigned vc = *reinterpret_cast<const unsigned*>(&feats[(size_t)lp[i+2]*768 + co4]);
    unsigned vd = *reinterpret_cast<const unsigned*>(&feats[(size_t)lp[i+3]*768 + co4]);
    ACC(va) ACC(vb) ACC(vc) ACC(vd)
  }
  for (; i < b1; i++){
    unsigned v = *reinterpret_cast<const unsigned*>(&feats[(size_t)lp[i]*768 + co4]);
    ACC(v)
  }
  #undef ACC
  int gs = b*196 + m;
  float* ms = &meansum[(size_t)gs*768 + co4];
  unsigned* mv = reinterpret_cast<unsigned*>(&maxv[(size_t)gs*768 + co4]);
  atomicAdd(&ms[0], s0); atomicAdd(&ms[1], s1);
  atomicAdd(&ms[2], s2); atomicAdd(&ms[3], s3);
  atomicMax(&mv[0], __float_as_uint(m0)); atomicMax(&mv[1], __float_as_uint(m1));
  atomicMax(&mv[2], __float_as_uint(m2)); atomicMax(&mv[3], __float_as_uint(m3));
}

// ---------------- fusion GEMM via bf16 MFMA, K-split; concat built inline from
// meansum/maxv/counts during A staging
__launch_bounds__(256)
__global__ void fusion_mfma_k(const float* __restrict__ meansum, const float* __restrict__ maxv,
                              const float* __restrict__ counts, const float* __restrict__ fw,
                              float* __restrict__ partial){
  __shared__ ushort SM2[2*128*72];      // AL (concat rows) | BL (fw rows)
  ushort* AL = SM2;
  ushort* BL = SM2 + 128*72;
  int tid = threadIdx.x;
  int lane = tid & 63, wave = tid >> 6;
  int wc = wave >> 1, wp = wave & 1;       // wc: m-half, wp: co-half
  int q = lane >> 4, l15 = lane & 15;
  int co0 = blockIdx.x * 128;
  int m0  = blockIdx.y * 128;
  int ksz = blockIdx.z;
  floatx4 acc[4][4];
  for (int i=0;i<4;i++) for (int j=0;j<4;j++) acc[i][j] = (floatx4){0.f,0.f,0.f,0.f};

  for (int kb=0; kb<3; kb++){
    int k0 = ksz*192 + kb*64;
    __syncthreads();
    #pragma unroll
    for (int i=0;i<4;i++){
      int idx = tid + 256*i;                 // 0..1023
      int row = idx >> 3, c8 = (idx & 7) * 8;
      int gm = m0 + row;
      float4 a0 = make_float4(0.f,0.f,0.f,0.f), a1 = a0;
      if (gm < 392){
        int k = k0 + c8;                     // chunk never straddles 768 boundary
        if (k < 768){
          float invc = 1.f / fmaxf(counts[gm], 1.f);
          a0 = *reinterpret_cast<const float4*>(&meansum[gm*768 + k]);
          a1 = *reinterpret_cast<const float4*>(&meansum[gm*768 + k + 4]);
          a0.x*=invc; a0.y*=invc; a0.z*=invc; a0.w*=invc;
          a1.x*=invc; a1.y*=invc; a1.z*=invc; a1.w*=invc;
        } else {
          a0 = *reinterpret_cast<const float4*>(&maxv[gm*768 + k - 768]);
          a1 = *reinterpret_cast<const float4*>(&maxv[gm*768 + k - 768 + 4]);
        }
      }
      ushort ua[8] = { f2bf(a0.x),f2bf(a0.y),f2bf(a0.z),f2bf(a0.w),
                       f2bf(a1.x),f2bf(a1.y),f2bf(a1.z),f2bf(a1.w) };
      *reinterpret_cast<uint4*>(&AL[row*72 + c8]) = *reinterpret_cast<uint4*>(ua);
      float4 b0 = *reinterpret_cast<const float4*>(&fw[(co0+row)*1536 + k0 + c8]);
      float4 b1 = *reinterpret_cast<const float4*>(&fw[(co0+row)*1536 + k0 + c8 + 4]);
      ushort ub[8] = { f2bf(b0.x),f2bf(b0.y),f2bf(b0.z),f2bf(b0.w),
                       f2bf(b1.x),f2bf(b1.y),f2bf(b1.z),f2bf(b1.w) };
      *reinterpret_cast<uint4*>(&BL[row*72 + c8]) = *reinterpret_cast<uint4*>(ub);
    }
    __syncthreads();
    #pragma unroll
    for (int ks=0; ks<64; ks+=32){
      short8 af[4], bfr[4];
      #pragma unroll
      for (int f=0; f<4; f++)
        af[f] = *reinterpret_cast<const short8*>(&AL[(wc*64+f*16+l15)*72 + ks + q*8]);
      #pragma unroll
      for (int f=0; f<4; f++)
        bfr[f] = *reinterpret_cast<const short8*>(&BL[(wp*64+f*16+l15)*72 + ks + q*8]);
      #pragma unroll
      for (int fm=0; fm<4; fm++)
        #pragma unroll
        for (int fn=0; fn<4; fn++)
          acc[fm][fn] = __builtin_amdgcn_mfma_f32_16x16x32_bf16(af[fm], bfr[fn], acc[fm][fn], 0,0,0);
    }
  }
  float* pp = &partial[(size_t)ksz * 301056];
  #pragma unroll
  for (int fm=0; fm<4; fm++){
    #pragma unroll
    for (int r2=0; r2<4; r2++){
      int m = m0 + wc*64 + fm*16 + q*4 + r2;
      if (m >= 392) continue;
      #pragma unroll
      for (int fn=0; fn<4; fn++){
        int co = co0 + wp*64 + fn*16 + l15;
        pp[(size_t)m*768 + co] = acc[fm][fn][r2];
      }
    }
  }
}

// ---------------- fusion epilogue: sum 8 K-split partials, bias, W_k scale, positional add
__global__ void fuse_ep_k(const float* __restrict__ partial, const float* __restrict__ fb,
                          const float* __restrict__ sims, const float* __restrict__ counts,
                          const float* __restrict__ cent, const float* __restrict__ pw,
                          const float* __restrict__ pb, float* __restrict__ out){
  int t = blockIdx.x*256 + threadIdx.x;    // 392*768 exactly
  int gm = t / 768, co = t % 768;
  float s = 0.f;
  #pragma unroll
  for (int k=0;k<8;k++) s += partial[(size_t)k*301056 + t];
  float wk = sims[gm] / fmaxf(counts[gm], 1.f);
  float cx = cent[gm*2 + 0] * (1.f/224.f);
  float cy = cent[gm*2 + 1] * (1.f/224.f);
  out[t] = (s + fb[co]) * wk + cx*pw[co*2] + cy*pw[co*2+1] + pb[co];
}

extern "C" void kernel_launch(void* const* d_in, const int* in_sizes, int n_in,
                              void* d_out, int out_size, void* d_ws, size_t ws_size,
                              hipStream_t stream){
  const float* img  = (const float*)d_in[0];
  const int*   seg  = (const int*)  d_in[1];
  const float* cent = (const float*)d_in[2];
  const float* c1w  = (const float*)d_in[3];
  const float* c1b  = (const float*)d_in[4];
  const float* bn1g = (const float*)d_in[5];
  const float* bn1b = (const float*)d_in[6];
  const float* bn1m = (const float*)d_in[7];
  const float* bn1v = (const float*)d_in[8];
  const float* c2w  = (const float*)d_in[9];
  const float* c2b  = (const float*)d_in[10];
  const float* bn2g = (const float*)d_in[11];
  const float* bn2b = (const float*)d_in[12];
  const float* bn2m = (const float*)d_in[13];
  const float* bn2v = (const float*)d_in[14];
  const float* ew   = (const float*)d_in[15];
  const float* pw   = (const float*)d_in[16];
  const float* pb   = (const float*)d_in[17];
  const float* fwp  = (const float*)d_in[18];
  const float* fbp  = (const float*)d_in[19];
  float* out = (float*)d_out;
  char* ws = (char*)d_ws;

  ushort* xbf    = (ushort*)(ws + 0);          //  12,845,056
  ushort* wt2    = (ushort*)(ws + 12845056);   //     884,736
  float*  bias2  = (float*) (ws + 13729792);   //       3,072
  float*  meansum= (float*) (ws + 13732864);   //   1,204,224  (memset region start)
  float*  maxv   = (float*) (ws + 14937088);   //   1,204,224
  float*  counts = (float*) (ws + 16141312);   //       1,568
  float*  sims   = (float*) (ws + 16142880);   //       1,568
  int*    scnt   = (int*)   (ws + 16144448);   //       3,136  (memset region end)
  int*    offs   = (int*)   (ws + 16147584);   //       3,200
  int*    curs   = (int*)   (ws + 16150784);   //       3,136
  int*    list   = (int*)   (ws + 16154112);   //     401,408  (global px indices)
  ushort* wA     = (ushort*)(ws + 16154112);   //       4,096 (aliases list; dead after conv1)
  float*  bias1  = (float*) (ws + 16158208);   //         256 (aliases list; dead after conv1)
  unsigned char* feats = (unsigned char*)(ws + 16555520);  // 77,070,336 (fp8 e4m3)
  float*  partial= (float*) (ws + 16555520);   //   9,633,792 (aliases feats; used after pooling)

  (void)hipMemsetAsync(ws + 13732864, 0, 2414720, stream);
  prep_k<<<1736, 256, 0, stream>>>(c2w, c2b, bn2g, bn2b, bn2m, bn2v, wt2, bias2,
                                   c1w, c1b, bn1g, bn1b, bn1m, bn1v, wA, bias1);
  conv1_k<<<392, 256, 0, stream>>>(img, wA, bias1, xbf);
  edge_k<<<392, 256, 0, stream>>>(img, seg, ew, out, counts, sims, scnt);
  scan_k<<<2, 256, 0, stream>>>(scnt, offs, curs);
  scatter_k<<<392, 256, 0, stream>>>(seg, curs, list);
  conv2_k<<<dim3(784, 6), 256, 0, stream>>>(xbf, wt2, bias2, feats);
  pool_k<<<dim3(196, 8, 2), 192, 0, stream>>>(feats, list, offs, meansum, maxv);
  fusion_mfma_k<<<dim3(6, 4, 8), 256, 0, stream>>>(meansum, maxv, counts, fwp, partial);
  fuse_ep_k<<<1176, 256, 0, stream>>>(partial, fbp, sims, counts, cent, pw, pb, out);
}

// Round 16
// 341.955 us; speedup vs baseline: 1.1268x; 1.1268x over previous
//
#include <hip/hip_runtime.h>
#include <hip/hip_fp8.h>

#define B_ 2
#define H_ 224
#define W_ 224
#define HW_ 50176
#define E_ 768
#define M_ 196

typedef __attribute__((ext_vector_type(8))) short short8;
typedef __attribute__((ext_vector_type(4))) float floatx4;

__device__ __forceinline__ float bf2f(ushort u){ return __uint_as_float(((unsigned)u)<<16); }
__device__ __forceinline__ ushort f2bf(float f){
  unsigned b = __float_as_uint(f);
  b += 0x7fffu + ((b>>16)&1u);
  return (ushort)(b>>16);
}
__device__ __forceinline__ unsigned char f2f8(float f){
  __hip_fp8_e4m3 t(f);
  return (unsigned char)t.__x;
}
__device__ __forceinline__ float f82f(unsigned char b){
  __hip_fp8_e4m3 t; t.__x = (__hip_fp8_storage_t)b;
  return (float)t;
}

// async global->LDS 16B (direct-to-shared DMA; LDS dst = wave-uniform base + lane*16)
__device__ __forceinline__ void ld_g2l16(const void* g, void* l){
  __builtin_amdgcn_global_load_lds((const __attribute__((address_space(1))) unsigned int*)g,
                                   (__attribute__((address_space(3))) unsigned int*)l, 16, 0, 0);
}

// ---------------- merged prep + edge kernel (independent work, one dispatch):
// blocks 0..1727: fold BN2 into conv2 weights, layout wt2[tap][kc][co][8]
// blocks 1728..1735: fold BN1 -> A[64 co][32 k]
// blocks 1736..2127: edge conv + gradient_map + similarity + per-seg stats
__global__ void prep_edge_k(const float* __restrict__ w2, const float* __restrict__ cb2,
                            const float* __restrict__ g2, const float* __restrict__ be2,
                            const float* __restrict__ mn2, const float* __restrict__ vr2,
                            ushort* __restrict__ wt2, float* __restrict__ bias2,
                            const float* __restrict__ w1, const float* __restrict__ cb1,
                            const float* __restrict__ g1, const float* __restrict__ be1,
                            const float* __restrict__ mn1, const float* __restrict__ vr1,
                            ushort* __restrict__ wA, float* __restrict__ bias1,
                            const float* __restrict__ img, const int* __restrict__ seg,
                            const float* __restrict__ ew, float* __restrict__ out,
                            float* __restrict__ counts, float* __restrict__ sims,
                            int* __restrict__ scnt){
  __shared__ float cnt[196], ssum[196];
  int tid = threadIdx.x;
  if (blockIdx.x < 1728){
    int t = blockIdx.x*256 + tid;              // 768*576 exactly
    int co = t / 576, kp = t % 576;
    int tap = kp >> 6, ci = kp & 63;
    float inv = g2[co] * rsqrtf(vr2[co] + 1e-5f);
    wt2[((tap*8 + (ci>>3))*768 + co)*8 + (ci&7)] = f2bf(w2[co*576 + ci*9 + tap] * inv);
    if (kp == 0) bias2[co] = cb2[co]*inv + be2[co] - mn2[co]*inv;
    return;
  }
  if (blockIdx.x < 1736){
    int t = (blockIdx.x-1728)*256 + tid;       // 2048 exactly
    int co = t >> 5, k = t & 31;
    float inv = g1[co] * rsqrtf(vr1[co] + 1e-5f);
    float val = 0.f;
    if (k < 27){
      int tap = k / 3, ci = k % 3;
      val = w1[co*27 + ci*9 + tap] * inv;
    }
    wA[co*32 + k] = f2bf(val);
    if (k == 0) bias1[co] = cb1[co]*inv + be1[co] - mn1[co]*inv;
    return;
  }
  // ---- edge path
  if (tid < 196){ cnt[tid]=0.f; ssum[tid]=0.f; }
  __syncthreads();
  int p = (blockIdx.x-1736)*256 + tid;
  int b = p / HW_; int r = p % HW_; int h = r / W_; int w = r % W_;
  float e0=0.f, e1=0.f;
  #pragma unroll
  for (int ky=0;ky<3;ky++){
    int hh=h+ky-1;
    #pragma unroll
    for (int kx=0;kx<3;kx++){
      int ww=w+kx-1;
      float gv=0.f;
      if (hh>=0&&hh<H_&&ww>=0&&ww<W_){
        int base = b*3*HW_ + hh*W_ + ww;
        gv=(img[base]+img[base+HW_]+img[base+2*HW_])*(1.f/3.f);
      }
      e0 += gv*ew[ky*3+kx];
      e1 += gv*ew[9+ky*3+kx];
    }
  }
  float gm = sqrtf(e0*e0+e1*e1+1e-8f);
  out[301056 + p] = gm;
  int sg = seg[p];
  out[401408 + p] = (float)sg;
  float sim = fminf(fmaxf(1.f-gm,0.f),1.f);
  atomicAdd(&cnt[sg], 1.f);
  atomicAdd(&ssum[sg], sim);
  __syncthreads();
  if (tid < 196){
    int gid = b*196 + tid;
    float c = cnt[tid];
    atomicAdd(&counts[gid], c);
    atomicAdd(&sims[gid], ssum[tid]);
    atomicAdd(&scnt[b*196+tid], (int)c);
  }
}

// ---------------- conv1 + BN1 + ReLU via bf16 MFMA implicit GEMM (K=27 pad 32)
__launch_bounds__(256)
__global__ void conv1_k(const float* __restrict__ img, const ushort* __restrict__ wA,
                        const float* __restrict__ bias1, ushort* __restrict__ xbf){
  __shared__ float HL[3*18*20];          // fp32 halo, row pad 20
  __shared__ ushort IC[256*40];          // im2col [px][32k pad40]
  __shared__ ushort AW[64*40];           // weights [co][32k pad40]
  __shared__ float b1s[64];
  int tid = threadIdx.x;
  int b = blockIdx.x / 196, tile = blockIdx.x % 196;
  int tr = tile / 14, tc = tile % 14;
  int h0 = tr*16, w0 = tc*16;
  for (int idx = tid; idx < 972; idx += 256){
    int ci = idx / 324, rem = idx % 324;
    int r = rem / 18, c = rem % 18;
    int hh = h0 + r - 1, ww = w0 + c - 1;
    float v = (hh>=0 && hh<H_ && ww>=0 && ww<W_) ? img[((b*3+ci)*H_+hh)*W_+ww] : 0.f;
    HL[ci*360 + r*20 + c] = v;
  }
  {
    int row = tid >> 2, cp = (tid&3)*8;
    uint4 v = *reinterpret_cast<const uint4*>(&wA[row*32 + cp]);
    *reinterpret_cast<uint4*>(&AW[row*40 + cp]) = v;
  }
  if (tid < 64) b1s[tid] = bias1[tid];
  __syncthreads();
  {
    int pr = tid >> 4, pc = tid & 15;
    ushort tmp[32];
    #pragma unroll
    for (int ky=0; ky<3; ky++)
      #pragma unroll
      for (int kx=0; kx<3; kx++)
        #pragma unroll
        for (int ci=0; ci<3; ci++)
          tmp[(ky*3+kx)*3+ci] = f2bf(HL[ci*360 + (pr+ky)*20 + (pc+kx)]);
    #pragma unroll
    for (int k=27; k<32; k++) tmp[k] = 0;
    #pragma unroll
    for (int j=0; j<4; j++)
      *reinterpret_cast<uint4*>(&IC[tid*40 + j*8]) = *reinterpret_cast<const uint4*>(&tmp[j*8]);
  }
  __syncthreads();
  int lane = tid & 63, wave = tid >> 6;
  int q = lane >> 4, l15 = lane & 15;
  short8 af[4], bfr[4];
  #pragma unroll
  for (int f=0; f<4; f++)
    af[f] = *reinterpret_cast<const short8*>(&AW[(f*16+l15)*40 + q*8]);
  #pragma unroll
  for (int f=0; f<4; f++)
    bfr[f] = *reinterpret_cast<const short8*>(&IC[(wave*64+f*16+l15)*40 + q*8]);
  floatx4 acc[4][4];
  #pragma unroll
  for (int fc=0; fc<4; fc++)
    #pragma unroll
    for (int fp=0; fp<4; fp++){
      floatx4 z = (floatx4){0.f,0.f,0.f,0.f};
      acc[fc][fp] = __builtin_amdgcn_mfma_f32_16x16x32_bf16(af[fc], bfr[fp], z, 0,0,0);
    }
  #pragma unroll
  for (int fp=0; fp<4; fp++){
    int pxl = wave*64 + fp*16 + l15;
    size_t gp = (size_t)b*HW_ + (size_t)(h0 + (pxl>>4))*W_ + (w0 + (pxl&15));
    #pragma unroll
    for (int fc=0; fc<4; fc++){
      int co4 = fc*16 + q*4;
      ushort o[4];
      #pragma unroll
      for (int r=0; r<4; r++) o[r] = f2bf(fmaxf(acc[fc][fp][r] + b1s[co4+r], 0.f));
      *reinterpret_cast<uint2*>(&xbf[gp*64 + co4]) = *reinterpret_cast<const uint2*>(o);
    }
  }
}

// ---------------- per-batch exclusive scan of segment counts
__global__ void scan_k(const int* __restrict__ scnt, int* __restrict__ offs, int* __restrict__ curs){
  __shared__ int a[256];
  int s = blockIdx.x, tid = threadIdx.x;
  a[tid] = (tid<196)? scnt[s*196+tid] : 0;
  __syncthreads();
  for (int d=1; d<256; d<<=1){
    int v = a[tid];
    int u = (tid>=d)? a[tid-d] : 0;
    __syncthreads();
    a[tid] = v+u;
    __syncthreads();
  }
  if (tid<=196) offs[s*200+tid] = tid ? a[tid-1] : 0;
  if (tid<196)  curs[s*196+tid] = tid ? a[tid-1] : 0;
}

// ---------------- scatter global pixel indices into per-(batch,segment) lists
__global__ void scatter_k(const int* __restrict__ seg, int* __restrict__ curs, int* __restrict__ list){
  int p = blockIdx.x*256+threadIdx.x;
  int b = p / HW_;
  int pos = atomicAdd(&curs[b*196+seg[p]], 1);
  list[b*HW_ + pos] = p;            // global pixel index
}

// ---------------- conv2 (dilated 3x3, 64->768) + BN2 + ReLU via bf16 MFMA implicit GEMM
// v4+fp8 (best measured: 113.5 us, FETCH 53 MB, WRITE 82 MB ~= ideal 77):
// plane LDS layout, half-tap W double buffer via global_load_lds, fully unrolled
// 18 half-steps, fp8-e4m3 epilogue — one co-block writes each 128 B feats line
// COMPLETELY, which is what keeps WRITE at ideal. 3 blocks/CU. Occupancy/barrier
// "fixes" (R10/R11/R12/R15) all lost more in L2 traffic than they gained.
__launch_bounds__(256, 3)
__global__ void conv2_k(const ushort* __restrict__ xbf, const ushort* __restrict__ wt2,
                        const float* __restrict__ bias2, unsigned char* __restrict__ feats){
  // XH: 8 planes x 240 px x 16B = 30720 B ; WL: 2 buf x 4 planes x 128 co x 16B = 16384 B
  __shared__ ushort SM[15360 + 8192];
  ushort* XH = SM;
  ushort* WL = SM + 15360;
  int tid = threadIdx.x;
  int lane = tid & 63, wave = tid >> 6;
  int wc = wave >> 1, wp = wave & 1;
  int q = lane >> 4, l15 = lane & 15;
  int bt = blockIdx.x / 392, tile = blockIdx.x % 392;
  int tr = tile / 14, tc = tile % 14;
  int co0 = blockIdx.y * 128;
  int h0 = tr*8, w0 = tc*16;

  // ---- stage X halo once: thread=px reads full 128B pixel row, writes 8 chunk planes
  {
    int px = tid;
    if (px < 240){
      int hr = px / 20, wcol = px % 20;
      int hh = h0 + hr - 2, ww = w0 + wcol - 2;
      bool ok = (hh>=0 && hh<H_ && ww>=0 && ww<W_);
      const uint4* src = reinterpret_cast<const uint4*>(&xbf[(((size_t)bt*H_+hh)*W_+ww)*64]);
      #pragma unroll
      for (int chl=0; chl<8; chl++){
        uint4 val = ok ? src[chl] : make_uint4(0u,0u,0u,0u);
        *reinterpret_cast<uint4*>(&XH[chl*1920 + px*8]) = val;
      }
    }
  }
  // ---- prefetch W half-step 0 into buf 0 (async, direct-to-LDS, lane-contiguous)
  #pragma unroll
  for (int j=0;j<2;j++){
    int idx = tid + 256*j;                           // 0..511 = kc_local*128 + co_local
    int srci = (((idx>>7))*768 + co0 + (idx&127))*8; // tap 0, half 0
    ld_g2l16(&wt2[srci], &WL[(idx & ~63)*8]);
  }
  __syncthreads();

  floatx4 acc[4][4];
  for (int i=0;i<4;i++) for (int j=0;j<4;j++) acc[i][j] = (floatx4){0.f,0.f,0.f,0.f};

  // per-lane invariant bases (ushort indices)
  int abase = q*1024 + (wc*64 + l15)*8;            // W: + bsel*4096 + f*128
  int xbase = q*1920 + (wp*80 + l15)*8;            // X: + half*7680 + (dyr*20+dxr)*8 + f*160

  #pragma unroll
  for (int hs = 0; hs < 18; hs++){
    const int tap = hs >> 1, half = hs & 1;
    const int bsel = hs & 1;
    if (hs < 17){                                  // prefetch next half-tap
      const int ntap = (hs+1) >> 1, nhalf = (hs+1) & 1, nb = (hs+1) & 1;
      #pragma unroll
      for (int j=0;j<2;j++){
        int idx = tid + 256*j;
        int srci = ((ntap*8 + nhalf*4 + (idx>>7))*768 + co0 + (idx&127))*8;
        ld_g2l16(&wt2[srci], &WL[nb*4096 + (idx & ~63)*8]);
      }
    }
    const int dyr = (tap/3)*2, dxr = (tap%3)*2;
    const int xoff = half*7680 + (dyr*20 + dxr)*8; // compile-time (unrolled)
    short8 af[4], bx[4];
    #pragma unroll
    for (int f=0; f<4; f++)
      af[f] = *reinterpret_cast<const short8*>(&WL[bsel*4096 + abase + f*128]);
    #pragma unroll
    for (int f=0; f<4; f++)
      bx[f] = *reinterpret_cast<const short8*>(&XH[xbase + xoff + f*160]);
    #pragma unroll
    for (int fc=0; fc<4; fc++)
      #pragma unroll
      for (int fp=0; fp<4; fp++)
        acc[fc][fp] = __builtin_amdgcn_mfma_f32_16x16x32_bf16(af[fc], bx[fp], acc[fc][fp], 0,0,0);
    __syncthreads();
  }

  // epilogue: bias + relu, fp8 pack, direct 4B stores (co = wc*64+fc*16+q*4+r)
  #pragma unroll
  for (int fc=0; fc<4; fc++){
    float4 bs = *reinterpret_cast<const float4*>(&bias2[co0 + wc*64 + fc*16 + q*4]);
    #pragma unroll
    for (int fp=0; fp<4; fp++){
      int pxl = wp*64 + fp*16 + l15;
      size_t pgl = (size_t)bt*HW_ + (size_t)(tr*8 + (pxl>>4))*W_ + tc*16 + (pxl&15);
      unsigned ob = (unsigned)f2f8(fmaxf(acc[fc][fp][0] + bs.x, 0.f))
                  | ((unsigned)f2f8(fmaxf(acc[fc][fp][1] + bs.y, 0.f)) << 8)
                  | ((unsigned)f2f8(fmaxf(acc[fc][fp][2] + bs.z, 0.f)) << 16)
                  | ((unsigned)f2f8(fmaxf(acc[fc][fp][3] + bs.w, 0.f)) << 24);
      *reinterpret_cast<unsigned*>(&feats[pgl*768 + co0 + wc*64 + fc*16 + q*4]) = ob;
    }
  }
}

// ---------------- gather pooling: full-image lists, 8-way split, fp8 feats (4B/lane)
__global__ void pool_k(const unsigned char* __restrict__ feats, const int* __restrict__ list,
                       const int* __restrict__ offs, float* __restrict__ meansum,
                       float* __restrict__ maxv){
  int m = blockIdx.x, qu = blockIdx.y, b = blockIdx.z, tid = threadIdx.x;
  int base = offs[b*200+m], end = offs[b*200+m+1];
  int len = end - base;
  int b0 = base + ((len*qu) >> 3);
  int b1 = base + ((len*(qu+1)) >> 3);
  const int* lp = &list[b*HW_];
  int co4 = tid*4;
  float s0=0.f,s1=0.f,s2=0.f,s3=0.f;
  float m0=0.f,m1=0.f,m2=0.f,m3=0.f;
  int i = b0;
  #define ACC(v) { \
    float f0=f82f((unsigned char)((v)&0xff)),      f1=f82f((unsigned char)(((v)>>8)&0xff)); \
    float f2=f82f((unsigned char)(((v)>>16)&0xff)), f3=f82f((unsigned char)((v)>>24)); \
    s0+=f0; s1+=f1; s2+=f2; s3+=f3; \
    m0=fmaxf(m0,f0); m1=fmaxf(m1,f1); m2=fmaxf(m2,f2); m3=fmaxf(m3,f3); }
  for (; i+3 < b1; i += 4){
    unsigned va = *reinterpret_cast<const unsigned*>(&feats[(size_t)lp[i  ]*768 + co4]);
    unsigned vb = *reinterpret_cast<const unsigned*>(&feats[(size_t)lp[i+1]*768 + co4]);
    unsigned vc = *reinterpret_cast<const unsigned*>(&feats[(size_t)lp[i+2]*768 + co4]);
    unsigned vd = *reinterpret_cast<const unsigned*>(&feats[(size_t)lp[i+3]*768 + co4]);
    ACC(va) ACC(vb) ACC(vc) ACC(vd)
  }
  for (; i < b1; i++){
    unsigned v = *reinterpret_cast<const unsigned*>(&feats[(size_t)lp[i]*768 + co4]);
    ACC(v)
  }
  #undef ACC
  int gs = b*196 + m;
  float* ms = &meansum[(size_t)gs*768 + co4];
  unsigned* mv = reinterpret_cast<unsigned*>(&maxv[(size_t)gs*768 + co4]);
  atomicAdd(&ms[0], s0); atomicAdd(&ms[1], s1);
  atomicAdd(&ms[2], s2); atomicAdd(&ms[3], s3);
  atomicMax(&mv[0], __float_as_uint(m0)); atomicMax(&mv[1], __float_as_uint(m1));
  atomicMax(&mv[2], __float_as_uint(m2)); atomicMax(&mv[3], __float_as_uint(m3));
}

// ---------------- fusion GEMM via bf16 MFMA, K-split; concat built inline from
// meansum/maxv/counts during A staging
__launch_bounds__(256)
__global__ void fusion_mfma_k(const float* __restrict__ meansum, const float* __restrict__ maxv,
                              const float* __restrict__ counts, const float* __restrict__ fw,
                              float* __restrict__ partial){
  __shared__ ushort SM2[2*128*72];      // AL (concat rows) | BL (fw rows)
  ushort* AL = SM2;
  ushort* BL = SM2 + 128*72;
  int tid = threadIdx.x;
  int lane = tid & 63, wave = tid >> 6;
  int wc = wave >> 1, wp = wave & 1;       // wc: m-half, wp: co-half
  int q = lane >> 4, l15 = lane & 15;
  int co0 = blockIdx.x * 128;
  int m0  = blockIdx.y * 128;
  int ksz = blockIdx.z;
  floatx4 acc[4][4];
  for (int i=0;i<4;i++) for (int j=0;j<4;j++) acc[i][j] = (floatx4){0.f,0.f,0.f,0.f};

  for (int kb=0; kb<3; kb++){
    int k0 = ksz*192 + kb*64;
    __syncthreads();
    #pragma unroll
    for (int i=0;i<4;i++){
      int idx = tid + 256*i;                 // 0..1023
      int row = idx >> 3, c8 = (idx & 7) * 8;
      int gm = m0 + row;
      float4 a0 = make_float4(0.f,0.f,0.f,0.f), a1 = a0;
      if (gm < 392){
        int k = k0 + c8;                     // chunk never straddles 768 boundary
        if (k < 768){
          float invc = 1.f / fmaxf(counts[gm], 1.f);
          a0 = *reinterpret_cast<const float4*>(&meansum[gm*768 + k]);
          a1 = *reinterpret_cast<const float4*>(&meansum[gm*768 + k + 4]);
          a0.x*=invc; a0.y*=invc; a0.z*=invc; a0.w*=invc;
          a1.x*=invc; a1.y*=invc; a1.z*=invc; a1.w*=invc;
        } else {
          a0 = *reinterpret_cast<const float4*>(&maxv[gm*768 + k - 768]);
          a1 = *reinterpret_cast<const float4*>(&maxv[gm*768 + k - 768 + 4]);
        }
      }
      ushort ua[8] = { f2bf(a0.x),f2bf(a0.y),f2bf(a0.z),f2bf(a0.w),
                       f2bf(a1.x),f2bf(a1.y),f2bf(a1.z),f2bf(a1.w) };
      *reinterpret_cast<uint4*>(&AL[row*72 + c8]) = *reinterpret_cast<uint4*>(ua);
      float4 b0 = *reinterpret_cast<const float4*>(&fw[(co0+row)*1536 + k0 + c8]);
      float4 b1 = *reinterpret_cast<const float4*>(&fw[(co0+row)*1536 + k0 + c8 + 4]);
      ushort ub[8] = { f2bf(b0.x),f2bf(b0.y),f2bf(b0.z),f2bf(b0.w),
                       f2bf(b1.x),f2bf(b1.y),f2bf(b1.z),f2bf(b1.w) };
      *reinterpret_cast<uint4*>(&BL[row*72 + c8]) = *reinterpret_cast<uint4*>(ub);
    }
    __syncthreads();
    #pragma unroll
    for (int ks=0; ks<64; ks+=32){
      short8 af[4], bfr[4];
      #pragma unroll
      for (int f=0; f<4; f++)
        af[f] = *reinterpret_cast<const short8*>(&AL[(wc*64+f*16+l15)*72 + ks + q*8]);
      #pragma unroll
      for (int f=0; f<4; f++)
        bfr[f] = *reinterpret_cast<const short8*>(&BL[(wp*64+f*16+l15)*72 + ks + q*8]);
      #pragma unroll
      for (int fm=0; fm<4; fm++)
        #pragma unroll
        for (int fn=0; fn<4; fn++)
          acc[fm][fn] = __builtin_amdgcn_mfma_f32_16x16x32_bf16(af[fm], bfr[fn], acc[fm][fn], 0,0,0);
    }
  }
  float* pp = &partial[(size_t)ksz * 301056];
  #pragma unroll
  for (int fm=0; fm<4; fm++){
    #pragma unroll
    for (int r2=0; r2<4; r2++){
      int m = m0 + wc*64 + fm*16 + q*4 + r2;
      if (m >= 392) continue;
      #pragma unroll
      for (int fn=0; fn<4; fn++){
        int co = co0 + wp*64 + fn*16 + l15;
        pp[(size_t)m*768 + co] = acc[fm][fn][r2];
      }
    }
  }
}

// ---------------- fusion epilogue: sum 8 K-split partials, bias, W_k scale, positional add
__global__ void fuse_ep_k(const float* __restrict__ partial, const float* __restrict__ fb,
                          const float* __restrict__ sims, const float* __restrict__ counts,
                          const float* __restrict__ cent, const float* __restrict__ pw,
                          const float* __restrict__ pb, float* __restrict__ out){
  int t = blockIdx.x*256 + threadIdx.x;    // 392*768 exactly
  int gm = t / 768, co = t % 768;
  float s = 0.f;
  #pragma unroll
  for (int k=0;k<8;k++) s += partial[(size_t)k*301056 + t];
  float wk = sims[gm] / fmaxf(counts[gm], 1.f);
  float cx = cent[gm*2 + 0] * (1.f/224.f);
  float cy = cent[gm*2 + 1] * (1.f/224.f);
  out[t] = (s + fb[co]) * wk + cx*pw[co*2] + cy*pw[co*2+1] + pb[co];
}

extern "C" void kernel_launch(void* const* d_in, const int* in_sizes, int n_in,
                              void* d_out, int out_size, void* d_ws, size_t ws_size,
                              hipStream_t stream){
  const float* img  = (const float*)d_in[0];
  const int*   seg  = (const int*)  d_in[1];
  const float* cent = (const float*)d_in[2];
  const float* c1w  = (const float*)d_in[3];
  const float* c1b  = (const float*)d_in[4];
  const float* bn1g = (const float*)d_in[5];
  const float* bn1b = (const float*)d_in[6];
  const float* bn1m = (const float*)d_in[7];
  const float* bn1v = (const float*)d_in[8];
  const float* c2w  = (const float*)d_in[9];
  const float* c2b  = (const float*)d_in[10];
  const float* bn2g = (const float*)d_in[11];
  const float* bn2b = (const float*)d_in[12];
  const float* bn2m = (const float*)d_in[13];
  const float* bn2v = (const float*)d_in[14];
  const float* ew   = (const float*)d_in[15];
  const float* pw   = (const float*)d_in[16];
  const float* pb   = (const float*)d_in[17];
  const float* fwp  = (const float*)d_in[18];
  const float* fbp  = (const float*)d_in[19];
  float* out = (float*)d_out;
  char* ws = (char*)d_ws;

  ushort* xbf    = (ushort*)(ws + 0);          //  12,845,056
  ushort* wt2    = (ushort*)(ws + 12845056);   //     884,736
  float*  bias2  = (float*) (ws + 13729792);   //       3,072
  float*  meansum= (float*) (ws + 13732864);   //   1,204,224  (memset region start)
  float*  maxv   = (float*) (ws + 14937088);   //   1,204,224
  float*  counts = (float*) (ws + 16141312);   //       1,568
  float*  sims   = (float*) (ws + 16142880);   //       1,568
  int*    scnt   = (int*)   (ws + 16144448);   //       3,136  (memset region end)
  int*    offs   = (int*)   (ws + 16147584);   //       3,200
  int*    curs   = (int*)   (ws + 16150784);   //       3,136
  int*    list   = (int*)   (ws + 16154112);   //     401,408  (global px indices)
  ushort* wA     = (ushort*)(ws + 16154112);   //       4,096 (aliases list; dead after conv1)
  float*  bias1  = (float*) (ws + 16158208);   //         256 (aliases list; dead after conv1)
  unsigned char* feats = (unsigned char*)(ws + 16555520);  // 77,070,336 (fp8 e4m3)
  float*  partial= (float*) (ws + 16555520);   //   9,633,792 (aliases feats; used after pooling)

  (void)hipMemsetAsync(ws + 13732864, 0, 2414720, stream);
  prep_edge_k<<<2128, 256, 0, stream>>>(c2w, c2b, bn2g, bn2b, bn2m, bn2v, wt2, bias2,
                                        c1w, c1b, bn1g, bn1b, bn1m, bn1v, wA, bias1,
                                        img, seg, ew, out, counts, sims, scnt);
  conv1_k<<<392, 256, 0, stream>>>(img, wA, bias1, xbf);
  scan_k<<<2, 256, 0, stream>>>(scnt, offs, curs);
  scatter_k<<<392, 256, 0, stream>>>(seg, curs, list);
  conv2_k<<<dim3(784, 6), 256, 0, stream>>>(xbf, wt2, bias2, feats);
  pool_k<<<dim3(196, 8, 2), 192, 0, stream>>>(feats, list, offs, meansum, maxv);
  fusion_mfma_k<<<dim3(6, 4, 8), 256, 0, stream>>>(meansum, maxv, counts, fwp, partial);
  fuse_ep_k<<<1176, 256, 0, stream>>>(partial, fbp, sims, counts, cent, pw, pb, out);
}

// Round 17
// 338.224 us; speedup vs baseline: 1.1392x; 1.0110x over previous
//
#include <hip/hip_runtime.h>
#include <hip/hip_fp8.h>

#define B_ 2
#define H_ 224
#define W_ 224
#define HW_ 50176
#define E_ 768
#define M_ 196

typedef __attribute__((ext_vector_type(8))) short short8;
typedef __attribute__((ext_vector_type(4))) float floatx4;

__device__ __forceinline__ float bf2f(ushort u){ return __uint_as_float(((unsigned)u)<<16); }
__device__ __forceinline__ ushort f2bf(float f){
  unsigned b = __float_as_uint(f);
  b += 0x7fffu + ((b>>16)&1u);
  return (ushort)(b>>16);
}
__device__ __forceinline__ unsigned char f2f8(float f){
  __hip_fp8_e4m3 t(f);
  return (unsigned char)t.__x;
}
__device__ __forceinline__ float f82f(unsigned char b){
  __hip_fp8_e4m3 t; t.__x = (__hip_fp8_storage_t)b;
  return (float)t;
}

// async global->LDS 16B (direct-to-shared DMA; LDS dst = wave-uniform base + lane*16)
__device__ __forceinline__ void ld_g2l16(const void* g, void* l){
  __builtin_amdgcn_global_load_lds((const __attribute__((address_space(1))) unsigned int*)g,
                                   (__attribute__((address_space(3))) unsigned int*)l, 16, 0, 0);
}

// ---------------- merged prep + edge kernel (independent work, one dispatch):
// blocks 0..47:  fold BN2 into conv2 weights -> wt2[tap][kc][co][8], 16 co/block,
//                coalesced reads (9216 contiguous floats) + LDS transpose +
//                coalesced 16B writes (was stride-9 scalar reads, 1728 blocks)
// block  48:     fold BN1 -> A[64 co][32 k]
// blocks 49..440: edge conv + gradient_map + similarity + per-seg stats
__global__ void prep_edge_k(const float* __restrict__ w2, const float* __restrict__ cb2,
                            const float* __restrict__ g2, const float* __restrict__ be2,
                            const float* __restrict__ mn2, const float* __restrict__ vr2,
                            ushort* __restrict__ wt2, float* __restrict__ bias2,
                            const float* __restrict__ w1, const float* __restrict__ cb1,
                            const float* __restrict__ g1, const float* __restrict__ be1,
                            const float* __restrict__ mn1, const float* __restrict__ vr1,
                            ushort* __restrict__ wA, float* __restrict__ bias1,
                            const float* __restrict__ img, const int* __restrict__ seg,
                            const float* __restrict__ ew, float* __restrict__ out,
                            float* __restrict__ counts, float* __restrict__ sims,
                            int* __restrict__ scnt){
  __shared__ ushort WT[9216];     // 16 co x 576 (co-major, src order)   18432 B
  __shared__ float aux[196];      // invs[16] for prep2 | cnt for edge
  __shared__ float aux2[196];     // ssum for edge
  int tid = threadIdx.x;
  if (blockIdx.x < 48){
    int co0 = blockIdx.x * 16;
    if (tid < 16){
      float inv = g2[co0+tid] * rsqrtf(vr2[co0+tid] + 1e-5f);
      aux[tid] = inv;
      bias2[co0+tid] = cb2[co0+tid]*inv + be2[co0+tid] - mn2[co0+tid]*inv;
    }
    __syncthreads();
    // coalesced read of 9216 contiguous floats, scale, bf16 into LDS (src order)
    #pragma unroll
    for (int j = 0; j < 36; j++){
      int idx = j*256 + tid;                 // 0..9215 = col*576 + (ci*9+tap)
      WT[idx] = f2bf(w2[(size_t)co0*576 + idx] * aux[idx/576]);
    }
    __syncthreads();
    // write 72 (tap,kc) chunks x 16 co x 8e as uint4 (256 B contiguous per chunk)
    #pragma unroll
    for (int j = 0; j < 5; j++){
      int o = j*256 + tid;                   // 0..1151 (last iter partial: 1152)
      if (o < 1152){
        int tapkc = o >> 4, col = o & 15;
        int tap = tapkc >> 3, kc = tapkc & 7;
        ushort tmp[8];
        #pragma unroll
        for (int e=0; e<8; e++)
          tmp[e] = WT[col*576 + (kc*8+e)*9 + tap];
        *reinterpret_cast<uint4*>(&wt2[(size_t)((tap*8 + kc)*768 + co0 + col)*8]) =
            *reinterpret_cast<const uint4*>(tmp);
      }
    }
    return;
  }
  if (blockIdx.x == 48){
    #pragma unroll
    for (int j = 0; j < 8; j++){
      int t = j*256 + tid;                   // 2048 exactly
      int co = t >> 5, k = t & 31;
      float inv = g1[co] * rsqrtf(vr1[co] + 1e-5f);
      float val = 0.f;
      if (k < 27){
        int tap = k / 3, ci = k % 3;
        val = w1[co*27 + ci*9 + tap] * inv;
      }
      wA[co*32 + k] = f2bf(val);
      if (k == 0) bias1[co] = cb1[co]*inv + be1[co] - mn1[co]*inv;
    }
    return;
  }
  // ---- edge path
  if (tid < 196){ aux[tid]=0.f; aux2[tid]=0.f; }
  __syncthreads();
  int p = (blockIdx.x-49)*256 + tid;
  int b = p / HW_; int r = p % HW_; int h = r / W_; int w = r % W_;
  float e0=0.f, e1=0.f;
  #pragma unroll
  for (int ky=0;ky<3;ky++){
    int hh=h+ky-1;
    #pragma unroll
    for (int kx=0;kx<3;kx++){
      int ww=w+kx-1;
      float gv=0.f;
      if (hh>=0&&hh<H_&&ww>=0&&ww<W_){
        int base = b*3*HW_ + hh*W_ + ww;
        gv=(img[base]+img[base+HW_]+img[base+2*HW_])*(1.f/3.f);
      }
      e0 += gv*ew[ky*3+kx];
      e1 += gv*ew[9+ky*3+kx];
    }
  }
  float gm = sqrtf(e0*e0+e1*e1+1e-8f);
  out[301056 + p] = gm;
  int sg = seg[p];
  out[401408 + p] = (float)sg;
  float sim = fminf(fmaxf(1.f-gm,0.f),1.f);
  atomicAdd(&aux[sg], 1.f);
  atomicAdd(&aux2[sg], sim);
  __syncthreads();
  if (tid < 196){
    int gid = b*196 + tid;
    float c = aux[tid];
    atomicAdd(&counts[gid], c);
    atomicAdd(&sims[gid], aux2[tid]);
    atomicAdd(&scnt[b*196+tid], (int)c);
  }
}

// ---------------- conv1 + BN1 + ReLU via bf16 MFMA implicit GEMM (K=27 pad 32)
__launch_bounds__(256)
__global__ void conv1_k(const float* __restrict__ img, const ushort* __restrict__ wA,
                        const float* __restrict__ bias1, ushort* __restrict__ xbf){
  __shared__ float HL[3*18*20];          // fp32 halo, row pad 20
  __shared__ ushort IC[256*40];          // im2col [px][32k pad40]
  __shared__ ushort AW[64*40];           // weights [co][32k pad40]
  __shared__ float b1s[64];
  int tid = threadIdx.x;
  int b = blockIdx.x / 196, tile = blockIdx.x % 196;
  int tr = tile / 14, tc = tile % 14;
  int h0 = tr*16, w0 = tc*16;
  for (int idx = tid; idx < 972; idx += 256){
    int ci = idx / 324, rem = idx % 324;
    int r = rem / 18, c = rem % 18;
    int hh = h0 + r - 1, ww = w0 + c - 1;
    float v = (hh>=0 && hh<H_ && ww>=0 && ww<W_) ? img[((b*3+ci)*H_+hh)*W_+ww] : 0.f;
    HL[ci*360 + r*20 + c] = v;
  }
  {
    int row = tid >> 2, cp = (tid&3)*8;
    uint4 v = *reinterpret_cast<const uint4*>(&wA[row*32 + cp]);
    *reinterpret_cast<uint4*>(&AW[row*40 + cp]) = v;
  }
  if (tid < 64) b1s[tid] = bias1[tid];
  __syncthreads();
  {
    int pr = tid >> 4, pc = tid & 15;
    ushort tmp[32];
    #pragma unroll
    for (int ky=0; ky<3; ky++)
      #pragma unroll
      for (int kx=0; kx<3; kx++)
        #pragma unroll
        for (int ci=0; ci<3; ci++)
          tmp[(ky*3+kx)*3+ci] = f2bf(HL[ci*360 + (pr+ky)*20 + (pc+kx)]);
    #pragma unroll
    for (int k=27; k<32; k++) tmp[k] = 0;
    #pragma unroll
    for (int j=0; j<4; j++)
      *reinterpret_cast<uint4*>(&IC[tid*40 + j*8]) = *reinterpret_cast<const uint4*>(&tmp[j*8]);
  }
  __syncthreads();
  int lane = tid & 63, wave = tid >> 6;
  int q = lane >> 4, l15 = lane & 15;
  short8 af[4], bfr[4];
  #pragma unroll
  for (int f=0; f<4; f++)
    af[f] = *reinterpret_cast<const short8*>(&AW[(f*16+l15)*40 + q*8]);
  #pragma unroll
  for (int f=0; f<4; f++)
    bfr[f] = *reinterpret_cast<const short8*>(&IC[(wave*64+f*16+l15)*40 + q*8]);
  floatx4 acc[4][4];
  #pragma unroll
  for (int fc=0; fc<4; fc++)
    #pragma unroll
    for (int fp=0; fp<4; fp++){
      floatx4 z = (floatx4){0.f,0.f,0.f,0.f};
      acc[fc][fp] = __builtin_amdgcn_mfma_f32_16x16x32_bf16(af[fc], bfr[fp], z, 0,0,0);
    }
  #pragma unroll
  for (int fp=0; fp<4; fp++){
    int pxl = wave*64 + fp*16 + l15;
    size_t gp = (size_t)b*HW_ + (size_t)(h0 + (pxl>>4))*W_ + (w0 + (pxl&15));
    #pragma unroll
    for (int fc=0; fc<4; fc++){
      int co4 = fc*16 + q*4;
      ushort o[4];
      #pragma unroll
      for (int r=0; r<4; r++) o[r] = f2bf(fmaxf(acc[fc][fp][r] + b1s[co4+r], 0.f));
      *reinterpret_cast<uint2*>(&xbf[gp*64 + co4]) = *reinterpret_cast<const uint2*>(o);
    }
  }
}

// ---------------- per-batch exclusive scan of segment counts
__global__ void scan_k(const int* __restrict__ scnt, int* __restrict__ offs, int* __restrict__ curs){
  __shared__ int a[256];
  int s = blockIdx.x, tid = threadIdx.x;
  a[tid] = (tid<196)? scnt[s*196+tid] : 0;
  __syncthreads();
  for (int d=1; d<256; d<<=1){
    int v = a[tid];
    int u = (tid>=d)? a[tid-d] : 0;
    __syncthreads();
    a[tid] = v+u;
    __syncthreads();
  }
  if (tid<=196) offs[s*200+tid] = tid ? a[tid-1] : 0;
  if (tid<196)  curs[s*196+tid] = tid ? a[tid-1] : 0;
}

// ---------------- scatter global pixel indices into per-(batch,segment) lists
__global__ void scatter_k(const int* __restrict__ seg, int* __restrict__ curs, int* __restrict__ list){
  int p = blockIdx.x*256+threadIdx.x;
  int b = p / HW_;
  int pos = atomicAdd(&curs[b*196+seg[p]], 1);
  list[b*HW_ + pos] = p;            // global pixel index
}

// ---------------- conv2 (dilated 3x3, 64->768) + BN2 + ReLU via bf16 MFMA implicit GEMM
// v4+fp8 (best measured: 112 us, FETCH 53 MB, WRITE 82 MB ~= ideal 77):
// plane LDS layout, half-tap W double buffer via global_load_lds, fully unrolled
// 18 half-steps, fp8-e4m3 epilogue — one co-block writes each 128 B feats line
// COMPLETELY, which keeps WRITE at ideal. 3 blocks/CU. All occupancy/barrier
// "fixes" (R10/R11/R12/R15) lost more in L2 traffic than they gained. FROZEN.
__launch_bounds__(256, 3)
__global__ void conv2_k(const ushort* __restrict__ xbf, const ushort* __restrict__ wt2,
                        const float* __restrict__ bias2, unsigned char* __restrict__ feats){
  // XH: 8 planes x 240 px x 16B = 30720 B ; WL: 2 buf x 4 planes x 128 co x 16B = 16384 B
  __shared__ ushort SM[15360 + 8192];
  ushort* XH = SM;
  ushort* WL = SM + 15360;
  int tid = threadIdx.x;
  int lane = tid & 63, wave = tid >> 6;
  int wc = wave >> 1, wp = wave & 1;
  int q = lane >> 4, l15 = lane & 15;
  int bt = blockIdx.x / 392, tile = blockIdx.x % 392;
  int tr = tile / 14, tc = tile % 14;
  int co0 = blockIdx.y * 128;
  int h0 = tr*8, w0 = tc*16;

  // ---- stage X halo once: thread=px reads full 128B pixel row, writes 8 chunk planes
  {
    int px = tid;
    if (px < 240){
      int hr = px / 20, wcol = px % 20;
      int hh = h0 + hr - 2, ww = w0 + wcol - 2;
      bool ok = (hh>=0 && hh<H_ && ww>=0 && ww<W_);
      const uint4* src = reinterpret_cast<const uint4*>(&xbf[(((size_t)bt*H_+hh)*W_+ww)*64]);
      #pragma unroll
      for (int chl=0; chl<8; chl++){
        uint4 val = ok ? src[chl] : make_uint4(0u,0u,0u,0u);
        *reinterpret_cast<uint4*>(&XH[chl*1920 + px*8]) = val;
      }
    }
  }
  // ---- prefetch W half-step 0 into buf 0 (async, direct-to-LDS, lane-contiguous)
  #pragma unroll
  for (int j=0;j<2;j++){
    int idx = tid + 256*j;                           // 0..511 = kc_local*128 + co_local
    int srci = (((idx>>7))*768 + co0 + (idx&127))*8; // tap 0, half 0
    ld_g2l16(&wt2[srci], &WL[(idx & ~63)*8]);
  }
  __syncthreads();

  floatx4 acc[4][4];
  for (int i=0;i<4;i++) for (int j=0;j<4;j++) acc[i][j] = (floatx4){0.f,0.f,0.f,0.f};

  // per-lane invariant bases (ushort indices)
  int abase = q*1024 + (wc*64 + l15)*8;            // W: + bsel*4096 + f*128
  int xbase = q*1920 + (wp*80 + l15)*8;            // X: + half*7680 + (dyr*20+dxr)*8 + f*160

  #pragma unroll
  for (int hs = 0; hs < 18; hs++){
    const int tap = hs >> 1, half = hs & 1;
    const int bsel = hs & 1;
    if (hs < 17){                                  // prefetch next half-tap
      const int ntap = (hs+1) >> 1, nhalf = (hs+1) & 1, nb = (hs+1) & 1;
      #pragma unroll
      for (int j=0;j<2;j++){
        int idx = tid + 256*j;
        int srci = ((ntap*8 + nhalf*4 + (idx>>7))*768 + co0 + (idx&127))*8;
        ld_g2l16(&wt2[srci], &WL[nb*4096 + (idx & ~63)*8]);
      }
    }
    const int dyr = (tap/3)*2, dxr = (tap%3)*2;
    const int xoff = half*7680 + (dyr*20 + dxr)*8; // compile-time (unrolled)
    short8 af[4], bx[4];
    #pragma unroll
    for (int f=0; f<4; f++)
      af[f] = *reinterpret_cast<const short8*>(&WL[bsel*4096 + abase + f*128]);
    #pragma unroll
    for (int f=0; f<4; f++)
      bx[f] = *reinterpret_cast<const short8*>(&XH[xbase + xoff + f*160]);
    #pragma unroll
    for (int fc=0; fc<4; fc++)
      #pragma unroll
      for (int fp=0; fp<4; fp++)
        acc[fc][fp] = __builtin_amdgcn_mfma_f32_16x16x32_bf16(af[fc], bx[fp], acc[fc][fp], 0,0,0);
    __syncthreads();
  }

  // epilogue: bias + relu, fp8 pack, direct 4B stores (co = wc*64+fc*16+q*4+r)
  #pragma unroll
  for (int fc=0; fc<4; fc++){
    float4 bs = *reinterpret_cast<const float4*>(&bias2[co0 + wc*64 + fc*16 + q*4]);
    #pragma unroll
    for (int fp=0; fp<4; fp++){
      int pxl = wp*64 + fp*16 + l15;
      size_t pgl = (size_t)bt*HW_ + (size_t)(tr*8 + (pxl>>4))*W_ + tc*16 + (pxl&15);
      unsigned ob = (unsigned)f2f8(fmaxf(acc[fc][fp][0] + bs.x, 0.f))
                  | ((unsigned)f2f8(fmaxf(acc[fc][fp][1] + bs.y, 0.f)) << 8)
                  | ((unsigned)f2f8(fmaxf(acc[fc][fp][2] + bs.z, 0.f)) << 16)
                  | ((unsigned)f2f8(fmaxf(acc[fc][fp][3] + bs.w, 0.f)) << 24);
      *reinterpret_cast<unsigned*>(&feats[pgl*768 + co0 + wc*64 + fc*16 + q*4]) = ob;
    }
  }
}

// ---------------- gather pooling: full-image lists, 8-way split, fp8 feats (4B/lane)
__global__ void pool_k(const unsigned char* __restrict__ feats, const int* __restrict__ list,
                       const int* __restrict__ offs, float* __restrict__ meansum,
                       float* __restrict__ maxv){
  int m = blockIdx.x, qu = blockIdx.y, b = blockIdx.z, tid = threadIdx.x;
  int base = offs[b*200+m], end = offs[b*200+m+1];
  int len = end - base;
  int b0 = base + ((len*qu) >> 3);
  int b1 = base + ((len*(qu+1)) >> 3);
  const int* lp = &list[b*HW_];
  int co4 = tid*4;
  float s0=0.f,s1=0.f,s2=0.f,s3=0.f;
  float m0=0.f,m1=0.f,m2=0.f,m3=0.f;
  int i = b0;
  #define ACC(v) { \
    float f0=f82f((unsigned char)((v)&0xff)),      f1=f82f((unsigned char)(((v)>>8)&0xff)); \
    float f2=f82f((unsigned char)(((v)>>16)&0xff)), f3=f82f((unsigned char)((v)>>24)); \
    s0+=f0; s1+=f1; s2+=f2; s3+=f3; \
    m0=fmaxf(m0,f0); m1=fmaxf(m1,f1); m2=fmaxf(m2,f2); m3=fmaxf(m3,f3); }
  for (; i+3 < b1; i += 4){
    unsigned va = *reinterpret_cast<const unsigned*>(&feats[(size_t)lp[i  ]*768 + co4]);
    unsigned vb = *reinterpret_cast<const unsigned*>(&feats[(size_t)lp[i+1]*768 + co4]);
    unsigned vc = *reinterpret_cast<const unsigned*>(&feats[(size_t)lp[i+2]*768 + co4]);
    unsigned vd = *reinterpret_cast<const unsigned*>(&feats[(size_t)lp[i+3]*768 + co4]);
    ACC(va) ACC(vb) ACC(vc) ACC(vd)
  }
  for (; i < b1; i++){
    unsigned v = *reinterpret_cast<const unsigned*>(&feats[(size_t)lp[i]*768 + co4]);
    ACC(v)
  }
  #undef ACC
  int gs = b*196 + m;
  float* ms = &meansum[(size_t)gs*768 + co4];
  unsigned* mv = reinterpret_cast<unsigned*>(&maxv[(size_t)gs*768 + co4]);
  atomicAdd(&ms[0], s0); atomicAdd(&ms[1], s1);
  atomicAdd(&ms[2], s2); atomicAdd(&ms[3], s3);
  atomicMax(&mv[0], __float_as_uint(m0)); atomicMax(&mv[1], __float_as_uint(m1));
  atomicMax(&mv[2], __float_as_uint(m2)); atomicMax(&mv[3], __float_as_uint(m3));
}

// ---------------- fusion GEMM via bf16 MFMA, K-split; concat built inline from
// meansum/maxv/counts during A staging
__launch_bounds__(256)
__global__ void fusion_mfma_k(const float* __restrict__ meansum, const float* __restrict__ maxv,
                              const float* __restrict__ counts, const float* __restrict__ fw,
                              float* __restrict__ partial){
  __shared__ ushort SM2[2*128*72];      // AL (concat rows) | BL (fw rows)
  ushort* AL = SM2;
  ushort* BL = SM2 + 128*72;
  int tid = threadIdx.x;
  int lane = tid & 63, wave = tid >> 6;
  int wc = wave >> 1, wp = wave & 1;       // wc: m-half, wp: co-half
  int q = lane >> 4, l15 = lane & 15;
  int co0 = blockIdx.x * 128;
  int m0  = blockIdx.y * 128;
  int ksz = blockIdx.z;
  floatx4 acc[4][4];
  for (int i=0;i<4;i++) for (int j=0;j<4;j++) acc[i][j] = (floatx4){0.f,0.f,0.f,0.f};

  for (int kb=0; kb<3; kb++){
    int k0 = ksz*192 + kb*64;
    __syncthreads();
    #pragma unroll
    for (int i=0;i<4;i++){
      int idx = tid + 256*i;                 // 0..1023
      int row = idx >> 3, c8 = (idx & 7) * 8;
      int gm = m0 + row;
      float4 a0 = make_float4(0.f,0.f,0.f,0.f), a1 = a0;
      if (gm < 392){
        int k = k0 + c8;                     // chunk never straddles 768 boundary
        if (k < 768){
          float invc = 1.f / fmaxf(counts[gm], 1.f);
          a0 = *reinterpret_cast<const float4*>(&meansum[gm*768 + k]);
          a1 = *reinterpret_cast<const float4*>(&meansum[gm*768 + k + 4]);
          a0.x*=invc; a0.y*=invc; a0.z*=invc; a0.w*=invc;
          a1.x*=invc; a1.y*=invc; a1.z*=invc; a1.w*=invc;
        } else {
          a0 = *reinterpret_cast<const float4*>(&maxv[gm*768 + k - 768]);
          a1 = *reinterpret_cast<const float4*>(&maxv[gm*768 + k - 768 + 4]);
        }
      }
      ushort ua[8] = { f2bf(a0.x),f2bf(a0.y),f2bf(a0.z),f2bf(a0.w),
                       f2bf(a1.x),f2bf(a1.y),f2bf(a1.z),f2bf(a1.w) };
      *reinterpret_cast<uint4*>(&AL[row*72 + c8]) = *reinterpret_cast<uint4*>(ua);
      float4 b0 = *reinterpret_cast<const float4*>(&fw[(co0+row)*1536 + k0 + c8]);
      float4 b1 = *reinterpret_cast<const float4*>(&fw[(co0+row)*1536 + k0 + c8 + 4]);
      ushort ub[8] = { f2bf(b0.x),f2bf(b0.y),f2bf(b0.z),f2bf(b0.w),
                       f2bf(b1.x),f2bf(b1.y),f2bf(b1.z),f2bf(b1.w) };
      *reinterpret_cast<uint4*>(&BL[row*72 + c8]) = *reinterpret_cast<uint4*>(ub);
    }
    __syncthreads();
    #pragma unroll
    for (int ks=0; ks<64; ks+=32){
      short8 af[4], bfr[4];
      #pragma unroll
      for (int f=0; f<4; f++)
        af[f] = *reinterpret_cast<const short8*>(&AL[(wc*64+f*16+l15)*72 + ks + q*8]);
      #pragma unroll
      for (int f=0; f<4; f++)
        bfr[f] = *reinterpret_cast<const short8*>(&BL[(wp*64+f*16+l15)*72 + ks + q*8]);
      #pragma unroll
      for (int fm=0; fm<4; fm++)
        #pragma unroll
        for (int fn=0; fn<4; fn++)
          acc[fm][fn] = __builtin_amdgcn_mfma_f32_16x16x32_bf16(af[fm], bfr[fn], acc[fm][fn], 0,0,0);
    }
  }
  float* pp = &partial[(size_t)ksz * 301056];
  #pragma unroll
  for (int fm=0; fm<4; fm++){
    #pragma unroll
    for (int r2=0; r2<4; r2++){
      int m = m0 + wc*64 + fm*16 + q*4 + r2;
      if (m >= 392) continue;
      #pragma unroll
      for (int fn=0; fn<4; fn++){
        int co = co0 + wp*64 + fn*16 + l15;
        pp[(size_t)m*768 + co] = acc[fm][fn][r2];
      }
    }
  }
}

// ---------------- fusion epilogue: sum 8 K-split partials, bias, W_k scale, positional add
__global__ void fuse_ep_k(const float* __restrict__ partial, const float* __restrict__ fb,
                          const float* __restrict__ sims, const float* __restrict__ counts,
                          const float* __restrict__ cent, const float* __restrict__ pw,
                          const float* __restrict__ pb, float* __restrict__ out){
  int t = blockIdx.x*256 + threadIdx.x;    // 392*768 exactly
  int gm = t / 768, co = t % 768;
  float s = 0.f;
  #pragma unroll
  for (int k=0;k<8;k++) s += partial[(size_t)k*301056 + t];
  float wk = sims[gm] / fmaxf(counts[gm], 1.f);
  float cx = cent[gm*2 + 0] * (1.f/224.f);
  float cy = cent[gm*2 + 1] * (1.f/224.f);
  out[t] = (s + fb[co]) * wk + cx*pw[co*2] + cy*pw[co*2+1] + pb[co];
}

extern "C" void kernel_launch(void* const* d_in, const int* in_sizes, int n_in,
                              void* d_out, int out_size, void* d_ws, size_t ws_size,
                              hipStream_t stream){
  const float* img  = (const float*)d_in[0];
  const int*   seg  = (const int*)  d_in[1];
  const float* cent = (const float*)d_in[2];
  const float* c1w  = (const float*)d_in[3];
  const float* c1b  = (const float*)d_in[4];
  const float* bn1g = (const float*)d_in[5];
  const float* bn1b = (const float*)d_in[6];
  const float* bn1m = (const float*)d_in[7];
  const float* bn1v = (const float*)d_in[8];
  const float* c2w  = (const float*)d_in[9];
  const float* c2b  = (const float*)d_in[10];
  const float* bn2g = (const float*)d_in[11];
  const float* bn2b = (const float*)d_in[12];
  const float* bn2m = (const float*)d_in[13];
  const float* bn2v = (const float*)d_in[14];
  const float* ew   = (const float*)d_in[15];
  const float* pw   = (const float*)d_in[16];
  const float* pb   = (const float*)d_in[17];
  const float* fwp  = (const float*)d_in[18];
  const float* fbp  = (const float*)d_in[19];
  float* out = (float*)d_out;
  char* ws = (char*)d_ws;

  ushort* xbf    = (ushort*)(ws + 0);          //  12,845,056
  ushort* wt2    = (ushort*)(ws + 12845056);   //     884,736
  float*  bias2  = (float*) (ws + 13729792);   //       3,072
  float*  meansum= (float*) (ws + 13732864);   //   1,204,224  (memset region start)
  float*  maxv   = (float*) (ws + 14937088);   //   1,204,224
  float*  counts = (float*) (ws + 16141312);   //       1,568
  float*  sims   = (float*) (ws + 16142880);   //       1,568
  int*    scnt   = (int*)   (ws + 16144448);   //       3,136  (memset region end)
  int*    offs   = (int*)   (ws + 16147584);   //       3,200
  int*    curs   = (int*)   (ws + 16150784);   //       3,136
  int*    list   = (int*)   (ws + 16154112);   //     401,408  (global px indices)
  ushort* wA     = (ushort*)(ws + 16154112);   //       4,096 (aliases list; dead after conv1)
  float*  bias1  = (float*) (ws + 16158208);   //         256 (aliases list; dead after conv1)
  unsigned char* feats = (unsigned char*)(ws + 16555520);  // 77,070,336 (fp8 e4m3)
  float*  partial= (float*) (ws + 16555520);   //   9,633,792 (aliases feats; used after pooling)

  (void)hipMemsetAsync(ws + 13732864, 0, 2414720, stream);
  prep_edge_k<<<441, 256, 0, stream>>>(c2w, c2b, bn2g, bn2b, bn2m, bn2v, wt2, bias2,
                                       c1w, c1b, bn1g, bn1b, bn1m, bn1v, wA, bias1,
                                       img, seg, ew, out, counts, sims, scnt);
  conv1_k<<<392, 256, 0, stream>>>(img, wA, bias1, xbf);
  scan_k<<<2, 256, 0, stream>>>(scnt, offs, curs);
  scatter_k<<<392, 256, 0, stream>>>(seg, curs, list);
  conv2_k<<<dim3(784, 6), 256, 0, stream>>>(xbf, wt2, bias2, feats);
  pool_k<<<dim3(196, 8, 2), 192, 0, stream>>>(feats, list, offs, meansum, maxv);
  fusion_mfma_k<<<dim3(6, 4, 8), 256, 0, stream>>>(meansum, maxv, counts, fwp, partial);
  fuse_ep_k<<<1176, 256, 0, stream>>>(partial, fbp, sims, counts, cent, pw, pb, out);
}

// Round 18
// 330.542 us; speedup vs baseline: 1.1657x; 1.0232x over previous
//
#include <hip/hip_runtime.h>
#include <hip/hip_fp8.h>

#define B_ 2
#define H_ 224
#define W_ 224
#define HW_ 50176
#define E_ 768
#define M_ 196

typedef __attribute__((ext_vector_type(8))) short short8;
typedef __attribute__((ext_vector_type(4))) float floatx4;

__device__ __forceinline__ float bf2f(ushort u){ return __uint_as_float(((unsigned)u)<<16); }
__device__ __forceinline__ ushort f2bf(float f){
  unsigned b = __float_as_uint(f);
  b += 0x7fffu + ((b>>16)&1u);
  return (ushort)(b>>16);
}
__device__ __forceinline__ unsigned char f2f8(float f){
  __hip_fp8_e4m3 t(f);
  return (unsigned char)t.__x;
}
__device__ __forceinline__ float f82f(unsigned char b){
  __hip_fp8_e4m3 t; t.__x = (__hip_fp8_storage_t)b;
  return (float)t;
}

// async global->LDS 16B (direct-to-shared DMA; LDS dst = wave-uniform base + lane*16)
__device__ __forceinline__ void ld_g2l16(const void* g, void* l){
  __builtin_amdgcn_global_load_lds((const __attribute__((address_space(1))) unsigned int*)g,
                                   (__attribute__((address_space(3))) unsigned int*)l, 16, 0, 0);
}

// ---------------- merged prep + edge kernel (independent work, one dispatch):
// blocks 0..47:  fold BN2 into conv2 weights -> wt2[tap][kc][co][8] (coalesced)
// block  48:     fold BN1 -> A[64 co][32 k]
// blocks 49..440: edge conv + gradient_map + similarity + per-seg stats
__global__ void prep_edge_k(const float* __restrict__ w2, const float* __restrict__ cb2,
                            const float* __restrict__ g2, const float* __restrict__ be2,
                            const float* __restrict__ mn2, const float* __restrict__ vr2,
                            ushort* __restrict__ wt2, float* __restrict__ bias2,
                            const float* __restrict__ w1, const float* __restrict__ cb1,
                            const float* __restrict__ g1, const float* __restrict__ be1,
                            const float* __restrict__ mn1, const float* __restrict__ vr1,
                            ushort* __restrict__ wA, float* __restrict__ bias1,
                            const float* __restrict__ img, const int* __restrict__ seg,
                            const float* __restrict__ ew, float* __restrict__ out,
                            float* __restrict__ counts, float* __restrict__ sims,
                            int* __restrict__ scnt){
  __shared__ ushort WT[9216];     // 16 co x 576 (co-major, src order)
  __shared__ float aux[196];      // invs[16] for prep2 | cnt for edge
  __shared__ float aux2[196];     // ssum for edge
  int tid = threadIdx.x;
  if (blockIdx.x < 48){
    int co0 = blockIdx.x * 16;
    if (tid < 16){
      float inv = g2[co0+tid] * rsqrtf(vr2[co0+tid] + 1e-5f);
      aux[tid] = inv;
      bias2[co0+tid] = cb2[co0+tid]*inv + be2[co0+tid] - mn2[co0+tid]*inv;
    }
    __syncthreads();
    #pragma unroll
    for (int j = 0; j < 36; j++){
      int idx = j*256 + tid;                 // 0..9215 = col*576 + (ci*9+tap)
      WT[idx] = f2bf(w2[(size_t)co0*576 + idx] * aux[idx/576]);
    }
    __syncthreads();
    #pragma unroll
    for (int j = 0; j < 5; j++){
      int o = j*256 + tid;                   // 0..1151
      if (o < 1152){
        int tapkc = o >> 4, col = o & 15;
        int tap = tapkc >> 3, kc = tapkc & 7;
        ushort tmp[8];
        #pragma unroll
        for (int e=0; e<8; e++)
          tmp[e] = WT[col*576 + (kc*8+e)*9 + tap];
        *reinterpret_cast<uint4*>(&wt2[(size_t)((tap*8 + kc)*768 + co0 + col)*8]) =
            *reinterpret_cast<const uint4*>(tmp);
      }
    }
    return;
  }
  if (blockIdx.x == 48){
    #pragma unroll
    for (int j = 0; j < 8; j++){
      int t = j*256 + tid;                   // 2048 exactly
      int co = t >> 5, k = t & 31;
      float inv = g1[co] * rsqrtf(vr1[co] + 1e-5f);
      float val = 0.f;
      if (k < 27){
        int tap = k / 3, ci = k % 3;
        val = w1[co*27 + ci*9 + tap] * inv;
      }
      wA[co*32 + k] = f2bf(val);
      if (k == 0) bias1[co] = cb1[co]*inv + be1[co] - mn1[co]*inv;
    }
    return;
  }
  // ---- edge path
  if (tid < 196){ aux[tid]=0.f; aux2[tid]=0.f; }
  __syncthreads();
  int p = (blockIdx.x-49)*256 + tid;
  int b = p / HW_; int r = p % HW_; int h = r / W_; int w = r % W_;
  float e0=0.f, e1=0.f;
  #pragma unroll
  for (int ky=0;ky<3;ky++){
    int hh=h+ky-1;
    #pragma unroll
    for (int kx=0;kx<3;kx++){
      int ww=w+kx-1;
      float gv=0.f;
      if (hh>=0&&hh<H_&&ww>=0&&ww<W_){
        int base = b*3*HW_ + hh*W_ + ww;
        gv=(img[base]+img[base+HW_]+img[base+2*HW_])*(1.f/3.f);
      }
      e0 += gv*ew[ky*3+kx];
      e1 += gv*ew[9+ky*3+kx];
    }
  }
  float gm = sqrtf(e0*e0+e1*e1+1e-8f);
  out[301056 + p] = gm;
  int sg = seg[p];
  out[401408 + p] = (float)sg;
  float sim = fminf(fmaxf(1.f-gm,0.f),1.f);
  atomicAdd(&aux[sg], 1.f);
  atomicAdd(&aux2[sg], sim);
  __syncthreads();
  if (tid < 196){
    int gid = b*196 + tid;
    float c = aux[tid];
    atomicAdd(&counts[gid], c);
    atomicAdd(&sims[gid], aux2[tid]);
    atomicAdd(&scnt[b*196+tid], (int)c);
  }
}

// ---------------- conv1 + BN1 + ReLU via bf16 MFMA (blocks 2..393);
// blocks 0..1: per-batch exclusive scan of segment counts (independent)
__launch_bounds__(256)
__global__ void conv1_scan_k(const float* __restrict__ img, const ushort* __restrict__ wA,
                             const float* __restrict__ bias1, ushort* __restrict__ xbf,
                             const int* __restrict__ scnt, int* __restrict__ offs,
                             int* __restrict__ curs){
  __shared__ float HL[3*18*20];          // fp32 halo, row pad 20 (also scan's a[])
  __shared__ ushort IC[256*40];          // im2col [px][32k pad40]
  __shared__ ushort AW[64*40];           // weights [co][32k pad40]
  __shared__ float b1s[64];
  int tid = threadIdx.x;
  if (blockIdx.x < 2){
    // ---- scan path
    int* a = reinterpret_cast<int*>(HL);
    int s = blockIdx.x;
    a[tid] = (tid<196)? scnt[s*196+tid] : 0;
    __syncthreads();
    for (int d=1; d<256; d<<=1){
      int v = a[tid];
      int u = (tid>=d)? a[tid-d] : 0;
      __syncthreads();
      a[tid] = v+u;
      __syncthreads();
    }
    if (tid<=196) offs[s*200+tid] = tid ? a[tid-1] : 0;
    if (tid<196)  curs[s*196+tid] = tid ? a[tid-1] : 0;
    return;
  }
  int bid = blockIdx.x - 2;
  int b = bid / 196, tile = bid % 196;
  int tr = tile / 14, tc = tile % 14;
  int h0 = tr*16, w0 = tc*16;
  for (int idx = tid; idx < 972; idx += 256){
    int ci = idx / 324, rem = idx % 324;
    int r = rem / 18, c = rem % 18;
    int hh = h0 + r - 1, ww = w0 + c - 1;
    float v = (hh>=0 && hh<H_ && ww>=0 && ww<W_) ? img[((b*3+ci)*H_+hh)*W_+ww] : 0.f;
    HL[ci*360 + r*20 + c] = v;
  }
  {
    int row = tid >> 2, cp = (tid&3)*8;
    uint4 v = *reinterpret_cast<const uint4*>(&wA[row*32 + cp]);
    *reinterpret_cast<uint4*>(&AW[row*40 + cp]) = v;
  }
  if (tid < 64) b1s[tid] = bias1[tid];
  __syncthreads();
  {
    int pr = tid >> 4, pc = tid & 15;
    ushort tmp[32];
    #pragma unroll
    for (int ky=0; ky<3; ky++)
      #pragma unroll
      for (int kx=0; kx<3; kx++)
        #pragma unroll
        for (int ci=0; ci<3; ci++)
          tmp[(ky*3+kx)*3+ci] = f2bf(HL[ci*360 + (pr+ky)*20 + (pc+kx)]);
    #pragma unroll
    for (int k=27; k<32; k++) tmp[k] = 0;
    #pragma unroll
    for (int j=0; j<4; j++)
      *reinterpret_cast<uint4*>(&IC[tid*40 + j*8]) = *reinterpret_cast<const uint4*>(&tmp[j*8]);
  }
  __syncthreads();
  int lane = tid & 63, wave = tid >> 6;
  int q = lane >> 4, l15 = lane & 15;
  short8 af[4], bfr[4];
  #pragma unroll
  for (int f=0; f<4; f++)
    af[f] = *reinterpret_cast<const short8*>(&AW[(f*16+l15)*40 + q*8]);
  #pragma unroll
  for (int f=0; f<4; f++)
    bfr[f] = *reinterpret_cast<const short8*>(&IC[(wave*64+f*16+l15)*40 + q*8]);
  floatx4 acc[4][4];
  #pragma unroll
  for (int fc=0; fc<4; fc++)
    #pragma unroll
    for (int fp=0; fp<4; fp++){
      floatx4 z = (floatx4){0.f,0.f,0.f,0.f};
      acc[fc][fp] = __builtin_amdgcn_mfma_f32_16x16x32_bf16(af[fc], bfr[fp], z, 0,0,0);
    }
  #pragma unroll
  for (int fp=0; fp<4; fp++){
    int pxl = wave*64 + fp*16 + l15;
    size_t gp = (size_t)b*HW_ + (size_t)(h0 + (pxl>>4))*W_ + (w0 + (pxl&15));
    #pragma unroll
    for (int fc=0; fc<4; fc++){
      int co4 = fc*16 + q*4;
      ushort o[4];
      #pragma unroll
      for (int r=0; r<4; r++) o[r] = f2bf(fmaxf(acc[fc][fp][r] + b1s[co4+r], 0.f));
      *reinterpret_cast<uint2*>(&xbf[gp*64 + co4]) = *reinterpret_cast<const uint2*>(o);
    }
  }
}

// ---------------- conv2 (dilated 3x3, 64->768) + BN2 + ReLU via bf16 MFMA implicit GEMM
// v4+fp8 FROZEN (112 us, FETCH 53 MB, WRITE 82 MB ~= ideal 77; all occupancy/
// barrier changes lost more in L2 traffic than gained: R10/R11/R12/R15).
// grid (784, 7): y==0/x<392 runs the scatter stage (independent, needs curs
// from the previous dispatch); y>=1 is conv2 with co0=(y-1)*128.
__launch_bounds__(256, 3)
__global__ void conv2_scatter_k(const ushort* __restrict__ xbf, const ushort* __restrict__ wt2,
                                const float* __restrict__ bias2, unsigned char* __restrict__ feats,
                                const int* __restrict__ seg, int* __restrict__ curs,
                                int* __restrict__ list){
  // XH: 8 planes x 240 px x 16B = 30720 B ; WL: 2 buf x 4 planes x 128 co x 16B = 16384 B
  __shared__ ushort SM[15360 + 8192];
  ushort* XH = SM;
  ushort* WL = SM + 15360;
  int tid = threadIdx.x;
  if (blockIdx.y == 0){
    // ---- scatter path: global pixel indices into per-(batch,segment) lists
    if (blockIdx.x < 392){
      int p = blockIdx.x*256 + tid;
      int b = p / HW_;
      int pos = atomicAdd(&curs[b*196+seg[p]], 1);
      list[b*HW_ + pos] = p;
    }
    return;
  }
  int lane = tid & 63, wave = tid >> 6;
  int wc = wave >> 1, wp = wave & 1;
  int q = lane >> 4, l15 = lane & 15;
  int bt = blockIdx.x / 392, tile = blockIdx.x % 392;
  int tr = tile / 14, tc = tile % 14;
  int co0 = (blockIdx.y - 1) * 128;
  int h0 = tr*8, w0 = tc*16;

  // ---- stage X halo once: thread=px reads full 128B pixel row, writes 8 chunk planes
  {
    int px = tid;
    if (px < 240){
      int hr = px / 20, wcol = px % 20;
      int hh = h0 + hr - 2, ww = w0 + wcol - 2;
      bool ok = (hh>=0 && hh<H_ && ww>=0 && ww<W_);
      const uint4* src = reinterpret_cast<const uint4*>(&xbf[(((size_t)bt*H_+hh)*W_+ww)*64]);
      #pragma unroll
      for (int chl=0; chl<8; chl++){
        uint4 val = ok ? src[chl] : make_uint4(0u,0u,0u,0u);
        *reinterpret_cast<uint4*>(&XH[chl*1920 + px*8]) = val;
      }
    }
  }
  // ---- prefetch W half-step 0 into buf 0 (async, direct-to-LDS, lane-contiguous)
  #pragma unroll
  for (int j=0;j<2;j++){
    int idx = tid + 256*j;                           // 0..511 = kc_local*128 + co_local
    int srci = (((idx>>7))*768 + co0 + (idx&127))*8; // tap 0, half 0
    ld_g2l16(&wt2[srci], &WL[(idx & ~63)*8]);
  }
  __syncthreads();

  floatx4 acc[4][4];
  for (int i=0;i<4;i++) for (int j=0;j<4;j++) acc[i][j] = (floatx4){0.f,0.f,0.f,0.f};

  // per-lane invariant bases (ushort indices)
  int abase = q*1024 + (wc*64 + l15)*8;            // W: + bsel*4096 + f*128
  int xbase = q*1920 + (wp*80 + l15)*8;            // X: + half*7680 + (dyr*20+dxr)*8 + f*160

  #pragma unroll
  for (int hs = 0; hs < 18; hs++){
    const int tap = hs >> 1, half = hs & 1;
    const int bsel = hs & 1;
    if (hs < 17){                                  // prefetch next half-tap
      const int ntap = (hs+1) >> 1, nhalf = (hs+1) & 1, nb = (hs+1) & 1;
      #pragma unroll
      for (int j=0;j<2;j++){
        int idx = tid + 256*j;
        int srci = ((ntap*8 + nhalf*4 + (idx>>7))*768 + co0 + (idx&127))*8;
        ld_g2l16(&wt2[srci], &WL[nb*4096 + (idx & ~63)*8]);
      }
    }
    const int dyr = (tap/3)*2, dxr = (tap%3)*2;
    const int xoff = half*7680 + (dyr*20 + dxr)*8; // compile-time (unrolled)
    short8 af[4], bx[4];
    #pragma unroll
    for (int f=0; f<4; f++)
      af[f] = *reinterpret_cast<const short8*>(&WL[bsel*4096 + abase + f*128]);
    #pragma unroll
    for (int f=0; f<4; f++)
      bx[f] = *reinterpret_cast<const short8*>(&XH[xbase + xoff + f*160]);
    #pragma unroll
    for (int fc=0; fc<4; fc++)
      #pragma unroll
      for (int fp=0; fp<4; fp++)
        acc[fc][fp] = __builtin_amdgcn_mfma_f32_16x16x32_bf16(af[fc], bx[fp], acc[fc][fp], 0,0,0);
    __syncthreads();
  }

  // epilogue: bias + relu, fp8 pack, direct 4B stores (co = wc*64+fc*16+q*4+r)
  #pragma unroll
  for (int fc=0; fc<4; fc++){
    float4 bs = *reinterpret_cast<const float4*>(&bias2[co0 + wc*64 + fc*16 + q*4]);
    #pragma unroll
    for (int fp=0; fp<4; fp++){
      int pxl = wp*64 + fp*16 + l15;
      size_t pgl = (size_t)bt*HW_ + (size_t)(tr*8 + (pxl>>4))*W_ + tc*16 + (pxl&15);
      unsigned ob = (unsigned)f2f8(fmaxf(acc[fc][fp][0] + bs.x, 0.f))
                  | ((unsigned)f2f8(fmaxf(acc[fc][fp][1] + bs.y, 0.f)) << 8)
                  | ((unsigned)f2f8(fmaxf(acc[fc][fp][2] + bs.z, 0.f)) << 16)
                  | ((unsigned)f2f8(fmaxf(acc[fc][fp][3] + bs.w, 0.f)) << 24);
      *reinterpret_cast<unsigned*>(&feats[pgl*768 + co0 + wc*64 + fc*16 + q*4]) = ob;
    }
  }
}

// ---------------- gather pooling: full-image lists, 8-way split, fp8 feats (4B/lane)
__global__ void pool_k(const unsigned char* __restrict__ feats, const int* __restrict__ list,
                       const int* __restrict__ offs, float* __restrict__ meansum,
                       float* __restrict__ maxv){
  int m = blockIdx.x, qu = blockIdx.y, b = blockIdx.z, tid = threadIdx.x;
  int base = offs[b*200+m], end = offs[b*200+m+1];
  int len = end - base;
  int b0 = base + ((len*qu) >> 3);
  int b1 = base + ((len*(qu+1)) >> 3);
  const int* lp = &list[b*HW_];
  int co4 = tid*4;
  float s0=0.f,s1=0.f,s2=0.f,s3=0.f;
  float m0=0.f,m1=0.f,m2=0.f,m3=0.f;
  int i = b0;
  #define ACC(v) { \
    float f0=f82f((unsigned char)((v)&0xff)),      f1=f82f((unsigned char)(((v)>>8)&0xff)); \
    float f2=f82f((unsigned char)(((v)>>16)&0xff)), f3=f82f((unsigned char)((v)>>24)); \
    s0+=f0; s1+=f1; s2+=f2; s3+=f3; \
    m0=fmaxf(m0,f0); m1=fmaxf(m1,f1); m2=fmaxf(m2,f2); m3=fmaxf(m3,f3); }
  for (; i+3 < b1; i += 4){
    unsigned va = *reinterpret_cast<const unsigned*>(&feats[(size_t)lp[i  ]*768 + co4]);
    unsigned vb = *reinterpret_cast<const unsigned*>(&feats[(size_t)lp[i+1]*768 + co4]);
    unsigned vc = *reinterpret_cast<const unsigned*>(&feats[(size_t)lp[i+2]*768 + co4]);
    unsigned vd = *reinterpret_cast<const unsigned*>(&feats[(size_t)lp[i+3]*768 + co4]);
    ACC(va) ACC(vb) ACC(vc) ACC(vd)
  }
  for (; i < b1; i++){
    unsigned v = *reinterpret_cast<const unsigned*>(&feats[(size_t)lp[i]*768 + co4]);
    ACC(v)
  }
  #undef ACC
  int gs = b*196 + m;
  float* ms = &meansum[(size_t)gs*768 + co4];
  unsigned* mv = reinterpret_cast<unsigned*>(&maxv[(size_t)gs*768 + co4]);
  atomicAdd(&ms[0], s0); atomicAdd(&ms[1], s1);
  atomicAdd(&ms[2], s2); atomicAdd(&ms[3], s3);
  atomicMax(&mv[0], __float_as_uint(m0)); atomicMax(&mv[1], __float_as_uint(m1));
  atomicMax(&mv[2], __float_as_uint(m2)); atomicMax(&mv[3], __float_as_uint(m3));
}

// ---------------- fusion GEMM via bf16 MFMA, K-split; concat built inline from
// meansum/maxv/counts during A staging
__launch_bounds__(256)
__global__ void fusion_mfma_k(const float* __restrict__ meansum, const float* __restrict__ maxv,
                              const float* __restrict__ counts, const float* __restrict__ fw,
                              float* __restrict__ partial){
  __shared__ ushort SM2[2*128*72];      // AL (concat rows) | BL (fw rows)
  ushort* AL = SM2;
  ushort* BL = SM2 + 128*72;
  int tid = threadIdx.x;
  int lane = tid & 63, wave = tid >> 6;
  int wc = wave >> 1, wp = wave & 1;       // wc: m-half, wp: co-half
  int q = lane >> 4, l15 = lane & 15;
  int co0 = blockIdx.x * 128;
  int m0  = blockIdx.y * 128;
  int ksz = blockIdx.z;
  floatx4 acc[4][4];
  for (int i=0;i<4;i++) for (int j=0;j<4;j++) acc[i][j] = (floatx4){0.f,0.f,0.f,0.f};

  for (int kb=0; kb<3; kb++){
    int k0 = ksz*192 + kb*64;
    __syncthreads();
    #pragma unroll
    for (int i=0;i<4;i++){
      int idx = tid + 256*i;                 // 0..1023
      int row = idx >> 3, c8 = (idx & 7) * 8;
      int gm = m0 + row;
      float4 a0 = make_float4(0.f,0.f,0.f,0.f), a1 = a0;
      if (gm < 392){
        int k = k0 + c8;                     // chunk never straddles 768 boundary
        if (k < 768){
          float invc = 1.f / fmaxf(counts[gm], 1.f);
          a0 = *reinterpret_cast<const float4*>(&meansum[gm*768 + k]);
          a1 = *reinterpret_cast<const float4*>(&meansum[gm*768 + k + 4]);
          a0.x*=invc; a0.y*=invc; a0.z*=invc; a0.w*=invc;
          a1.x*=invc; a1.y*=invc; a1.z*=invc; a1.w*=invc;
        } else {
          a0 = *reinterpret_cast<const float4*>(&maxv[gm*768 + k - 768]);
          a1 = *reinterpret_cast<const float4*>(&maxv[gm*768 + k - 768 + 4]);
        }
      }
      ushort ua[8] = { f2bf(a0.x),f2bf(a0.y),f2bf(a0.z),f2bf(a0.w),
                       f2bf(a1.x),f2bf(a1.y),f2bf(a1.z),f2bf(a1.w) };
      *reinterpret_cast<uint4*>(&AL[row*72 + c8]) = *reinterpret_cast<uint4*>(ua);
      float4 b0 = *reinterpret_cast<const float4*>(&fw[(co0+row)*1536 + k0 + c8]);
      float4 b1 = *reinterpret_cast<const float4*>(&fw[(co0+row)*1536 + k0 + c8 + 4]);
      ushort ub[8] = { f2bf(b0.x),f2bf(b0.y),f2bf(b0.z),f2bf(b0.w),
                       f2bf(b1.x),f2bf(b1.y),f2bf(b1.z),f2bf(b1.w) };
      *reinterpret_cast<uint4*>(&BL[row*72 + c8]) = *reinterpret_cast<uint4*>(ub);
    }
    __syncthreads();
    #pragma unroll
    for (int ks=0; ks<64; ks+=32){
      short8 af[4], bfr[4];
      #pragma unroll
      for (int f=0; f<4; f++)
        af[f] = *reinterpret_cast<const short8*>(&AL[(wc*64+f*16+l15)*72 + ks + q*8]);
      #pragma unroll
      for (int f=0; f<4; f++)
        bfr[f] = *reinterpret_cast<const short8*>(&BL[(wp*64+f*16+l15)*72 + ks + q*8]);
      #pragma unroll
      for (int fm=0; fm<4; fm++)
        #pragma unroll
        for (int fn=0; fn<4; fn++)
          acc[fm][fn] = __builtin_amdgcn_mfma_f32_16x16x32_bf16(af[fm], bfr[fn], acc[fm][fn], 0,0,0);
    }
  }
  float* pp = &partial[(size_t)ksz * 301056];
  #pragma unroll
  for (int fm=0; fm<4; fm++){
    #pragma unroll
    for (int r2=0; r2<4; r2++){
      int m = m0 + wc*64 + fm*16 + q*4 + r2;
      if (m >= 392) continue;
      #pragma unroll
      for (int fn=0; fn<4; fn++){
        int co = co0 + wp*64 + fn*16 + l15;
        pp[(size_t)m*768 + co] = acc[fm][fn][r2];
      }
    }
  }
}

// ---------------- fusion epilogue: sum 8 K-split partials, bias, W_k scale, positional add
__global__ void fuse_ep_k(const float* __restrict__ partial, const float* __restrict__ fb,
                          const float* __restrict__ sims, const float* __restrict__ counts,
                          const float* __restrict__ cent, const float* __restrict__ pw,
                          const float* __restrict__ pb, float* __restrict__ out){
  int t = blockIdx.x*256 + threadIdx.x;    // 392*768 exactly
  int gm = t / 768, co = t % 768;
  float s = 0.f;
  #pragma unroll
  for (int k=0;k<8;k++) s += partial[(size_t)k*301056 + t];
  float wk = sims[gm] / fmaxf(counts[gm], 1.f);
  float cx = cent[gm*2 + 0] * (1.f/224.f);
  float cy = cent[gm*2 + 1] * (1.f/224.f);
  out[t] = (s + fb[co]) * wk + cx*pw[co*2] + cy*pw[co*2+1] + pb[co];
}

extern "C" void kernel_launch(void* const* d_in, const int* in_sizes, int n_in,
                              void* d_out, int out_size, void* d_ws, size_t ws_size,
                              hipStream_t stream){
  const float* img  = (const float*)d_in[0];
  const int*   seg  = (const int*)  d_in[1];
  const float* cent = (const float*)d_in[2];
  const float* c1w  = (const float*)d_in[3];
  const float* c1b  = (const float*)d_in[4];
  const float* bn1g = (const float*)d_in[5];
  const float* bn1b = (const float*)d_in[6];
  const float* bn1m = (const float*)d_in[7];
  const float* bn1v = (const float*)d_in[8];
  const float* c2w  = (const float*)d_in[9];
  const float* c2b  = (const float*)d_in[10];
  const float* bn2g = (const float*)d_in[11];
  const float* bn2b = (const float*)d_in[12];
  const float* bn2m = (const float*)d_in[13];
  const float* bn2v = (const float*)d_in[14];
  const float* ew   = (const float*)d_in[15];
  const float* pw   = (const float*)d_in[16];
  const float* pb   = (const float*)d_in[17];
  const float* fwp  = (const float*)d_in[18];
  const float* fbp  = (const float*)d_in[19];
  float* out = (float*)d_out;
  char* ws = (char*)d_ws;

  ushort* xbf    = (ushort*)(ws + 0);          //  12,845,056
  ushort* wt2    = (ushort*)(ws + 12845056);   //     884,736
  float*  bias2  = (float*) (ws + 13729792);   //       3,072
  float*  meansum= (float*) (ws + 13732864);   //   1,204,224  (memset region start)
  float*  maxv   = (float*) (ws + 14937088);   //   1,204,224
  float*  counts = (float*) (ws + 16141312);   //       1,568
  float*  sims   = (float*) (ws + 16142880);   //       1,568
  int*    scnt   = (int*)   (ws + 16144448);   //       3,136  (memset region end)
  int*    offs   = (int*)   (ws + 16147584);   //       3,200
  int*    curs   = (int*)   (ws + 16150784);   //       3,136
  int*    list   = (int*)   (ws + 16154112);   //     401,408  (global px indices)
  ushort* wA     = (ushort*)(ws + 16154112);   //       4,096 (aliases list; dead after conv1)
  float*  bias1  = (float*) (ws + 16158208);   //         256 (aliases list; dead after conv1)
  unsigned char* feats = (unsigned char*)(ws + 16555520);  // 77,070,336 (fp8 e4m3)
  float*  partial= (float*) (ws + 16555520);   //   9,633,792 (aliases feats; used after pooling)

  (void)hipMemsetAsync(ws + 13732864, 0, 2414720, stream);
  prep_edge_k<<<441, 256, 0, stream>>>(c2w, c2b, bn2g, bn2b, bn2m, bn2v, wt2, bias2,
                                       c1w, c1b, bn1g, bn1b, bn1m, bn1v, wA, bias1,
                                       img, seg, ew, out, counts, sims, scnt);
  conv1_scan_k<<<394, 256, 0, stream>>>(img, wA, bias1, xbf, scnt, offs, curs);
  conv2_scatter_k<<<dim3(784, 7), 256, 0, stream>>>(xbf, wt2, bias2, feats, seg, curs, list);
  pool_k<<<dim3(196, 8, 2), 192, 0, stream>>>(feats, list, offs, meansum, maxv);
  fusion_mfma_k<<<dim3(6, 4, 8), 256, 0, stream>>>(meansum, maxv, counts, fwp, partial);
  fuse_ep_k<<<1176, 256, 0, stream>>>(partial, fbp, sims, counts, cent, pw, pb, out);
}